// Round 1
// baseline (355.224 us; speedup 1.0000x reference)
//
#include <hip/hip_runtime.h>
#include <stdint.h>

typedef __bf16 bf8 __attribute__((ext_vector_type(8)));
typedef float f4 __attribute__((ext_vector_type(4)));
typedef unsigned short us8 __attribute__((ext_vector_type(8)));
typedef unsigned short us4 __attribute__((ext_vector_type(4)));

#define MFMA16(a, b, c) __builtin_amdgcn_mfma_f32_16x16x32_bf16(a, b, c, 0, 0, 0)

__device__ __forceinline__ unsigned short f2b(float f) {
  union { float f; unsigned u; } x; x.f = f;
  unsigned u = x.u;
  u += 0x7fffu + ((u >> 16) & 1u);   // RNE
  return (unsigned short)(u >> 16);
}
__device__ __forceinline__ float b2f(unsigned short h) {
  union { unsigned u; float f; } x; x.u = ((unsigned)h) << 16;
  return x.f;
}

// ---------------- fp32 -> bf16 convert (hidden states) ----------------
__global__ __launch_bounds__(256) void cvt_bf16_kernel(
    const float* __restrict__ x, unsigned short* __restrict__ y) {
  int i = blockIdx.x * 256 + threadIdx.x;          // one float4 per thread
  float4 v = ((const float4*)x)[i];
  us4 r = { f2b(v.x), f2b(v.y), f2b(v.z), f2b(v.w) };
  *(us4*)(y + (size_t)i * 4) = r;
}

// ---------------- fp32 W[k][n] -> bf16 Wt[n][k] ----------------
__global__ __launch_bounds__(256) void transpose_cvt_kernel(
    const float* __restrict__ W, unsigned short* __restrict__ Wt) {
  __shared__ float tile[32][33];
  int tx = threadIdx.x & 31, ty = threadIdx.x >> 5;   // 32 x 8
  int kb = blockIdx.x * 32, nb = blockIdx.y * 32;
#pragma unroll
  for (int j = 0; j < 32; j += 8)
    tile[ty + j][tx] = W[(size_t)(kb + ty + j) * 1024 + nb + tx];
  __syncthreads();
#pragma unroll
  for (int j = 0; j < 32; j += 8)
    Wt[(size_t)(nb + ty + j) * 1024 + kb + tx] = f2b(tile[tx][ty + j]);
}

// ---------------- QKV projection GEMM ----------------
// C = X(4096x1024) @ W(1024x1024) + bias ; written as bf16 (b,h,s,d)
#define LDSK 40   // padded LDS stride in bf16 elems (16B aligned, ~2-way banks)

__global__ __launch_bounds__(256) void gemm_qkv_kernel(
    const unsigned short* __restrict__ X,
    const unsigned short* __restrict__ Wqt, const unsigned short* __restrict__ Wkt,
    const unsigned short* __restrict__ Wvt,
    const float* __restrict__ bq, const float* __restrict__ bk,
    const float* __restrict__ bv,
    unsigned short* __restrict__ Qo, unsigned short* __restrict__ Ko,
    unsigned short* __restrict__ Vo) {
  const unsigned short* Wt; const float* bias; unsigned short* out;
  if (blockIdx.z == 0)      { Wt = Wqt; bias = bq; out = Qo; }
  else if (blockIdx.z == 1) { Wt = Wkt; bias = bk; out = Ko; }
  else                      { Wt = Wvt; bias = bv; out = Vo; }

  __shared__ unsigned short As[128 * LDSK];
  __shared__ unsigned short Bs[128 * LDSK];
  const int t = threadIdx.x;
  const int wave = t >> 6, lane = t & 63, quad = lane >> 4, l16 = lane & 15;
  const int wm = (wave >> 1) * 64, wn = (wave & 1) * 64;
  const int m0 = blockIdx.y * 128, n0 = blockIdx.x * 128;

  f4 acc[4][4];
#pragma unroll
  for (int mi = 0; mi < 4; ++mi)
#pragma unroll
    for (int ni = 0; ni < 4; ++ni) acc[mi][ni] = (f4)0.0f;

  for (int k0 = 0; k0 < 1024; k0 += 32) {
    __syncthreads();
#pragma unroll
    for (int it = 0; it < 2; ++it) {
      int chunk = t + it * 256;                  // 0..511
      int row = chunk >> 2, c8 = (chunk & 3) * 8;
      *(us8*)&As[row * LDSK + c8] =
          *(const us8*)&X[(size_t)(m0 + row) * 1024 + k0 + c8];
      *(us8*)&Bs[row * LDSK + c8] =
          *(const us8*)&Wt[(size_t)(n0 + row) * 1024 + k0 + c8];
    }
    __syncthreads();
    bf8 a[4], b[4];
#pragma unroll
    for (int mi = 0; mi < 4; ++mi)
      a[mi] = *(const bf8*)&As[(wm + mi * 16 + l16) * LDSK + quad * 8];
#pragma unroll
    for (int ni = 0; ni < 4; ++ni)
      b[ni] = *(const bf8*)&Bs[(wn + ni * 16 + l16) * LDSK + quad * 8];
#pragma unroll
    for (int mi = 0; mi < 4; ++mi)
#pragma unroll
      for (int ni = 0; ni < 4; ++ni)
        acc[mi][ni] = MFMA16(a[mi], b[ni], acc[mi][ni]);
  }
  // epilogue: C/D layout col=lane&15, row=quad*4+reg
#pragma unroll
  for (int ni = 0; ni < 4; ++ni) {
    int n = n0 + wn + ni * 16 + l16;
    float bv_ = bias[n];
    int h = n >> 6, d = n & 63;
#pragma unroll
    for (int mi = 0; mi < 4; ++mi) {
#pragma unroll
      for (int r = 0; r < 4; ++r) {
        int m = m0 + wm + mi * 16 + quad * 4 + r;
        int b_ = m >> 11, s = m & 2047;
        out[(size_t)(((b_ << 4) | h) * 2048 + s) * 64 + d] =
            f2b(acc[mi][ni][r] + bv_);
      }
    }
  }
}

// ---------------- RoPE in-place on Q and K ----------------
// x'[d] = x[d]*cos(s*f_d) - x[d^16]*sin(s*f_d), d in [0,32), f_d = 10000^(-d/32)
__global__ __launch_bounds__(256) void rope_kernel(
    unsigned short* __restrict__ Q, unsigned short* __restrict__ K) {
  int tid = blockIdx.x * 256 + threadIdx.x;   // 2^22 threads
  int d = tid & 31;
  int s = (tid >> 5) & 2047;
  int bh = (tid >> 16) & 31;
  unsigned short* X = (tid >> 21) ? K : Q;
  unsigned short* row = X + ((size_t)bh * 2048 + s) * 64;
  float x0 = b2f(row[d]);
  float x1 = b2f(row[d ^ 16]);
  // f = 2^(-d * log2(10000)/32)
  float f = exp2f(-(float)d * (13.287712379549449f / 32.0f));
  float ang = (float)s * f;
  float c = cosf(ang), sn = sinf(ang);
  row[d] = f2b(x0 * c - x1 * sn);   // same-wave loads precede store: safe in-place
}

// ---------------- causal flash attention ----------------
// grid: (32 q-tiles of 64 rows, 32 bh). 4 waves x 16 q-rows. Bc = 64.
__global__ __launch_bounds__(256) void flash_attn_kernel(
    const unsigned short* __restrict__ Q, const unsigned short* __restrict__ K,
    const unsigned short* __restrict__ V, unsigned short* __restrict__ ctx) {
  __shared__ unsigned short Ks[64 * 72];        // K[kk][d], stride 72
  __shared__ unsigned short Vt[64 * 72];        // V^T: Vt[d][kk]
  __shared__ unsigned short Ps[4 * 16 * 72];    // per-wave P tile

  const int t = threadIdx.x;
  const int wave = t >> 6, lane = t & 63, quad = lane >> 4, l16 = lane & 15;
  const int bh = blockIdx.y, b = bh >> 4, h = bh & 15;
  const int qbase = blockIdx.x * 64;

  const unsigned short* Qh = Q + (size_t)bh * 2048 * 64;
  const unsigned short* Kh = K + (size_t)bh * 2048 * 64;
  const unsigned short* Vh = V + (size_t)bh * 2048 * 64;

  const int qrow = qbase + wave * 16 + l16;
  const bf8 qa0 = *(const bf8*)&Qh[(size_t)qrow * 64 + quad * 8];
  const bf8 qa1 = *(const bf8*)&Qh[(size_t)qrow * 64 + 32 + quad * 8];

  f4 o[4];
#pragma unroll
  for (int dt = 0; dt < 4; ++dt) o[dt] = (f4)0.0f;
  float mrow[4], lrow[4];
#pragma unroll
  for (int r = 0; r < 4; ++r) { mrow[r] = -3e38f; lrow[r] = 0.0f; }
  const int row_base = qbase + wave * 16 + quad * 4;

  for (int k0 = 0; k0 <= qbase; k0 += 64) {
    __syncthreads();
#pragma unroll
    for (int it = 0; it < 2; ++it) {
      int chunk = t + it * 256;                 // 0..511
      int r = chunk >> 3, c8 = (chunk & 7) * 8;
      *(us8*)&Ks[r * 72 + c8] = *(const us8*)&Kh[(size_t)(k0 + r) * 64 + c8];
      us8 vv = *(const us8*)&Vh[(size_t)(k0 + r) * 64 + c8];
#pragma unroll
      for (int j = 0; j < 8; ++j) Vt[(c8 + j) * 72 + r] = vv[j];
    }
    __syncthreads();

    // S = Q K^T  (per wave: 16 x 64)
    f4 sc[4];
#pragma unroll
    for (int nt = 0; nt < 4; ++nt) {
      bf8 b0 = *(const bf8*)&Ks[(nt * 16 + l16) * 72 + quad * 8];
      bf8 b1 = *(const bf8*)&Ks[(nt * 16 + l16) * 72 + 32 + quad * 8];
      f4 z = (f4)0.0f;
      z = MFMA16(qa0, b0, z);
      z = MFMA16(qa1, b1, z);
      sc[nt] = z;
    }

    // scale + causal mask
    float sv[4][4];
#pragma unroll
    for (int nt = 0; nt < 4; ++nt) {
      int col = k0 + nt * 16 + l16;
#pragma unroll
      for (int r = 0; r < 4; ++r) {
        float v = sc[nt][r] * 0.125f;
        sv[nt][r] = (col > row_base + r) ? -3e38f : v;
      }
    }

    // online softmax: row max across 4 tiles then across the 16 lanes of the quad-group
    float mt[4], al[4];
#pragma unroll
    for (int r = 0; r < 4; ++r) {
      mt[r] = fmaxf(fmaxf(sv[0][r], sv[1][r]), fmaxf(sv[2][r], sv[3][r]));
#pragma unroll
      for (int off = 1; off < 16; off <<= 1)
        mt[r] = fmaxf(mt[r], __shfl_xor(mt[r], off));
      float mn = fmaxf(mrow[r], mt[r]);
      al[r] = __expf(mrow[r] - mn);
      mrow[r] = mn;
    }

    float ls[4] = {0.f, 0.f, 0.f, 0.f};
#pragma unroll
    for (int nt = 0; nt < 4; ++nt)
#pragma unroll
      for (int r = 0; r < 4; ++r) {
        float p = __expf(sv[nt][r] - mrow[r]);
        ls[r] += p;
        Ps[wave * 1152 + (quad * 4 + r) * 72 + nt * 16 + l16] = f2b(p);
      }
#pragma unroll
    for (int r = 0; r < 4; ++r) {
#pragma unroll
      for (int off = 1; off < 16; off <<= 1) ls[r] += __shfl_xor(ls[r], off);
      lrow[r] = lrow[r] * al[r] + ls[r];
    }
#pragma unroll
    for (int dt = 0; dt < 4; ++dt)
#pragma unroll
      for (int r = 0; r < 4; ++r) o[dt][r] *= al[r];

    __threadfence_block();   // order per-wave Ps writes before A-layout reads

    // O += P V   (P from per-wave LDS in A-layout, V^T from shared LDS)
    bf8 pa0 = *(const bf8*)&Ps[wave * 1152 + l16 * 72 + quad * 8];
    bf8 pa1 = *(const bf8*)&Ps[wave * 1152 + l16 * 72 + 32 + quad * 8];
#pragma unroll
    for (int dt = 0; dt < 4; ++dt) {
      bf8 vb0 = *(const bf8*)&Vt[(dt * 16 + l16) * 72 + quad * 8];
      bf8 vb1 = *(const bf8*)&Vt[(dt * 16 + l16) * 72 + 32 + quad * 8];
      o[dt] = MFMA16(pa0, vb0, o[dt]);
      o[dt] = MFMA16(pa1, vb1, o[dt]);
    }
  }

  // epilogue: ctx in (b, s, E) bf16
#pragma unroll
  for (int dt = 0; dt < 4; ++dt)
#pragma unroll
    for (int r = 0; r < 4; ++r) {
      float val = o[dt][r] / lrow[r];
      size_t idx = ((size_t)(b * 2048 + qbase + wave * 16 + quad * 4 + r)) * 1024 +
                   h * 64 + dt * 16 + l16;
      ctx[idx] = f2b(val);
    }
}

// ---------------- output projection GEMM (fp32 out) ----------------
__global__ __launch_bounds__(256) void gemm_out_kernel(
    const unsigned short* __restrict__ A,    // ctx bf16 4096x1024
    const unsigned short* __restrict__ Wt,   // Wd^T bf16 1024x1024
    const float* __restrict__ bias, float* __restrict__ out) {
  __shared__ unsigned short As[128 * LDSK];
  __shared__ unsigned short Bs[128 * LDSK];
  const int t = threadIdx.x;
  const int wave = t >> 6, lane = t & 63, quad = lane >> 4, l16 = lane & 15;
  const int wm = (wave >> 1) * 64, wn = (wave & 1) * 64;
  const int m0 = blockIdx.y * 128, n0 = blockIdx.x * 128;

  f4 acc[4][4];
#pragma unroll
  for (int mi = 0; mi < 4; ++mi)
#pragma unroll
    for (int ni = 0; ni < 4; ++ni) acc[mi][ni] = (f4)0.0f;

  for (int k0 = 0; k0 < 1024; k0 += 32) {
    __syncthreads();
#pragma unroll
    for (int it = 0; it < 2; ++it) {
      int chunk = t + it * 256;
      int row = chunk >> 2, c8 = (chunk & 3) * 8;
      *(us8*)&As[row * LDSK + c8] =
          *(const us8*)&A[(size_t)(m0 + row) * 1024 + k0 + c8];
      *(us8*)&Bs[row * LDSK + c8] =
          *(const us8*)&Wt[(size_t)(n0 + row) * 1024 + k0 + c8];
    }
    __syncthreads();
    bf8 a[4], b[4];
#pragma unroll
    for (int mi = 0; mi < 4; ++mi)
      a[mi] = *(const bf8*)&As[(wm + mi * 16 + l16) * LDSK + quad * 8];
#pragma unroll
    for (int ni = 0; ni < 4; ++ni)
      b[ni] = *(const bf8*)&Bs[(wn + ni * 16 + l16) * LDSK + quad * 8];
#pragma unroll
    for (int mi = 0; mi < 4; ++mi)
#pragma unroll
      for (int ni = 0; ni < 4; ++ni)
        acc[mi][ni] = MFMA16(a[mi], b[ni], acc[mi][ni]);
  }
#pragma unroll
  for (int ni = 0; ni < 4; ++ni) {
    int n = n0 + wn + ni * 16 + l16;
    float bv_ = bias[n];
#pragma unroll
    for (int mi = 0; mi < 4; ++mi) {
#pragma unroll
      for (int r = 0; r < 4; ++r) {
        int m = m0 + wm + mi * 16 + quad * 4 + r;
        out[(size_t)m * 1024 + n] = acc[mi][ni][r] + bv_;
      }
    }
  }
}

extern "C" void kernel_launch(void* const* d_in, const int* in_sizes, int n_in,
                              void* d_out, int out_size, void* d_ws, size_t ws_size,
                              hipStream_t stream) {
  const float* hidden = (const float*)d_in[0];
  const float* Wq = (const float*)d_in[1];
  const float* bq = (const float*)d_in[2];
  const float* Wk = (const float*)d_in[3];
  const float* bk = (const float*)d_in[4];
  const float* Wv = (const float*)d_in[5];
  const float* bv = (const float*)d_in[6];
  const float* Wd = (const float*)d_in[7];
  const float* bd = (const float*)d_in[8];
  float* out = (float*)d_out;

  char* ws = (char*)d_ws;
  unsigned short* Xb  = (unsigned short*)(ws);                    // 8 MB
  unsigned short* Wqt = (unsigned short*)(ws + ( 8ull << 20));    // 2 MB each
  unsigned short* Wkt = (unsigned short*)(ws + (10ull << 20));
  unsigned short* Wvt = (unsigned short*)(ws + (12ull << 20));
  unsigned short* Wdt = (unsigned short*)(ws + (14ull << 20));
  unsigned short* Qb  = (unsigned short*)(ws + (16ull << 20));    // 8 MB each
  unsigned short* Kb  = (unsigned short*)(ws + (24ull << 20));
  unsigned short* Vb  = (unsigned short*)(ws + (32ull << 20));
  unsigned short* Cb  = (unsigned short*)(ws + (40ull << 20));

  cvt_bf16_kernel<<<4096, 256, 0, stream>>>(hidden, Xb);
  dim3 tg(32, 32);
  transpose_cvt_kernel<<<tg, 256, 0, stream>>>(Wq, Wqt);
  transpose_cvt_kernel<<<tg, 256, 0, stream>>>(Wk, Wkt);
  transpose_cvt_kernel<<<tg, 256, 0, stream>>>(Wv, Wvt);
  transpose_cvt_kernel<<<tg, 256, 0, stream>>>(Wd, Wdt);
  gemm_qkv_kernel<<<dim3(8, 32, 3), 256, 0, stream>>>(
      Xb, Wqt, Wkt, Wvt, bq, bk, bv, Qb, Kb, Vb);
  rope_kernel<<<16384, 256, 0, stream>>>(Qb, Kb);
  flash_attn_kernel<<<dim3(32, 32), 256, 0, stream>>>(Qb, Kb, Vb, Cb);
  gemm_out_kernel<<<dim3(8, 32), 256, 0, stream>>>(Cb, Wdt, bd, out);
}

// Round 2
// 297.755 us; speedup vs baseline: 1.1930x; 1.1930x over previous
//
#include <hip/hip_runtime.h>
#include <stdint.h>

typedef __bf16 bf8 __attribute__((ext_vector_type(8)));
typedef float f4 __attribute__((ext_vector_type(4)));
typedef unsigned short us8 __attribute__((ext_vector_type(8)));
typedef unsigned short us4 __attribute__((ext_vector_type(4)));

#define MFMA16(a, b, c) __builtin_amdgcn_mfma_f32_16x16x32_bf16(a, b, c, 0, 0, 0)

__device__ __forceinline__ unsigned short f2b(float f) {
  union { float f; unsigned u; } x; x.f = f;
  unsigned u = x.u;
  u += 0x7fffu + ((u >> 16) & 1u);   // RNE
  return (unsigned short)(u >> 16);
}
__device__ __forceinline__ float b2f(unsigned short h) {
  union { unsigned u; float f; } x; x.u = ((unsigned)h) << 16;
  return x.f;
}

// ---------------- fp32 -> bf16 convert (hidden states) ----------------
__global__ __launch_bounds__(256) void cvt_bf16_kernel(
    const float* __restrict__ x, unsigned short* __restrict__ y) {
  int i = blockIdx.x * 256 + threadIdx.x;          // one float4 per thread
  float4 v = ((const float4*)x)[i];
  us4 r = { f2b(v.x), f2b(v.y), f2b(v.z), f2b(v.w) };
  *(us4*)(y + (size_t)i * 4) = r;
}

// ---------------- fp32 W[k][n] -> bf16 Wt[n][k] ----------------
__global__ __launch_bounds__(256) void transpose_cvt_kernel(
    const float* __restrict__ W, unsigned short* __restrict__ Wt) {
  __shared__ float tile[32][33];
  int tx = threadIdx.x & 31, ty = threadIdx.x >> 5;   // 32 x 8
  int kb = blockIdx.x * 32, nb = blockIdx.y * 32;
#pragma unroll
  for (int j = 0; j < 32; j += 8)
    tile[ty + j][tx] = W[(size_t)(kb + ty + j) * 1024 + nb + tx];
  __syncthreads();
#pragma unroll
  for (int j = 0; j < 32; j += 8)
    Wt[(size_t)(nb + ty + j) * 1024 + kb + tx] = f2b(tile[tx][ty + j]);
}

// ---------------- QKV projection GEMM (+ fused RoPE for Q,K) ----------------
// C = X(4096x1024) @ W(1024x1024) + bias ; written as bf16 (b,h,s,d)
#define LDSK 40   // padded LDS stride in bf16 elems (16B aligned, conflict-free)

__global__ __launch_bounds__(256) void gemm_qkv_kernel(
    const unsigned short* __restrict__ X,
    const unsigned short* __restrict__ Wqt, const unsigned short* __restrict__ Wkt,
    const unsigned short* __restrict__ Wvt,
    const float* __restrict__ bq, const float* __restrict__ bk,
    const float* __restrict__ bv,
    unsigned short* __restrict__ Qo, unsigned short* __restrict__ Ko,
    unsigned short* __restrict__ Vo) {
  const unsigned short* Wt; const float* bias; unsigned short* out;
  if (blockIdx.z == 0)      { Wt = Wqt; bias = bq; out = Qo; }
  else if (blockIdx.z == 1) { Wt = Wkt; bias = bk; out = Ko; }
  else                      { Wt = Wvt; bias = bv; out = Vo; }

  __shared__ unsigned short As[128 * LDSK];
  __shared__ unsigned short Bs[128 * LDSK];
  const int t = threadIdx.x;
  const int wave = t >> 6, lane = t & 63, quad = lane >> 4, l16 = lane & 15;
  const int wm = (wave >> 1) * 64, wn = (wave & 1) * 64;
  const int m0 = blockIdx.y * 128, n0 = blockIdx.x * 128;

  f4 acc[4][4];
#pragma unroll
  for (int mi = 0; mi < 4; ++mi)
#pragma unroll
    for (int ni = 0; ni < 4; ++ni) acc[mi][ni] = (f4)0.0f;

  for (int k0 = 0; k0 < 1024; k0 += 32) {
    __syncthreads();
#pragma unroll
    for (int it = 0; it < 2; ++it) {
      int chunk = t + it * 256;                  // 0..511
      int row = chunk >> 2, c8 = (chunk & 3) * 8;
      *(us8*)&As[row * LDSK + c8] =
          *(const us8*)&X[(size_t)(m0 + row) * 1024 + k0 + c8];
      *(us8*)&Bs[row * LDSK + c8] =
          *(const us8*)&Wt[(size_t)(n0 + row) * 1024 + k0 + c8];
    }
    __syncthreads();
    bf8 a[4], b[4];
#pragma unroll
    for (int mi = 0; mi < 4; ++mi)
      a[mi] = *(const bf8*)&As[(wm + mi * 16 + l16) * LDSK + quad * 8];
#pragma unroll
    for (int ni = 0; ni < 4; ++ni)
      b[ni] = *(const bf8*)&Bs[(wn + ni * 16 + l16) * LDSK + quad * 8];
#pragma unroll
    for (int mi = 0; mi < 4; ++mi)
#pragma unroll
      for (int ni = 0; ni < 4; ++ni)
        acc[mi][ni] = MFMA16(a[mi], b[ni], acc[mi][ni]);
  }

  // ---- epilogue: bias (+ RoPE for Q,K), C/D layout col=l16, row=quad*4+r ----
  float biasv[4];
#pragma unroll
  for (int ni = 0; ni < 4; ++ni) biasv[ni] = bias[n0 + wn + ni * 16 + l16];

  if (blockIdx.z < 2) {
    // d = ni*16 + l16 (wn&63==0). Pair (d, d^16) == registers (ni=0, ni=1).
    const float kr = 13.287712379549449f / 32.0f;   // log2(10000)/32
    const float f0 = exp2f(-(float)l16 * kr);
    const float f1 = exp2f(-(float)(l16 + 16) * kr);
#pragma unroll
    for (int mi = 0; mi < 4; ++mi) {
#pragma unroll
      for (int r = 0; r < 4; ++r) {
        int m = m0 + wm + mi * 16 + quad * 4 + r;
        float s = (float)(m & 2047);
        float s0, c0, s1, c1;
        __sincosf(s * f0, &s0, &c0);
        __sincosf(s * f1, &s1, &c1);
        float v0 = acc[mi][0][r] + biasv[0];
        float v1 = acc[mi][1][r] + biasv[1];
        acc[mi][0][r] = v0 * c0 - v1 * s0;
        acc[mi][1][r] = v1 * c1 - v0 * s1;
        acc[mi][2][r] += biasv[2];
        acc[mi][3][r] += biasv[3];
      }
    }
  } else {
#pragma unroll
    for (int mi = 0; mi < 4; ++mi)
#pragma unroll
      for (int ni = 0; ni < 4; ++ni)
#pragma unroll
        for (int r = 0; r < 4; ++r) acc[mi][ni][r] += biasv[ni];
  }

#pragma unroll
  for (int ni = 0; ni < 4; ++ni) {
    int n = n0 + wn + ni * 16 + l16;
    int h = n >> 6, d = n & 63;
#pragma unroll
    for (int mi = 0; mi < 4; ++mi) {
#pragma unroll
      for (int r = 0; r < 4; ++r) {
        int m = m0 + wm + mi * 16 + quad * 4 + r;
        int b_ = m >> 11, s = m & 2047;
        out[(size_t)(((b_ << 4) | h) * 2048 + s) * 64 + d] = f2b(acc[mi][ni][r]);
      }
    }
  }
}

// ---------------- causal flash attention ----------------
// Br=128 (4 waves x 32 rows, 2 A-frags each), Bc=64. 512 blocks, balanced map.
__global__ __launch_bounds__(256) void flash_attn_kernel(
    const unsigned short* __restrict__ Q, const unsigned short* __restrict__ K,
    const unsigned short* __restrict__ V, unsigned short* __restrict__ ctx) {
  __shared__ unsigned short Ks[64 * 72];          // K[kk][d]
  __shared__ unsigned short Vt[64 * 72];          // V^T: Vt[d][kk]
  __shared__ unsigned short Ps[4 * 32 * 72];      // per-wave P tile (32 rows)

  const int t = threadIdx.x;
  const int wave = t >> 6, lane = t & 63, quad = lane >> 4, l16 = lane & 15;

  // balanced qtile map: CU gets ids {c, c+256} -> j and j+8 -> qt in {k, 15-k};
  // k-tile counts (2qt+2) sum to 34 exactly for every CU.
  const int id = blockIdx.x;
  const int bh = id & 31;
  const int j = id >> 5;                          // 0..15
  const int qt = (j >> 3) ? (15 - (j & 7)) : (j & 7);
  const int qbase = qt * 128;
  const int b = bh >> 4, h = bh & 15;

  const unsigned short* Qh = Q + (size_t)bh * 2048 * 64;
  const unsigned short* Kh = K + (size_t)bh * 2048 * 64;
  const unsigned short* Vh = V + (size_t)bh * 2048 * 64;

  const int wrow0 = qbase + wave * 32;            // wave's first q-row
  bf8 qa[2][2];
#pragma unroll
  for (int f = 0; f < 2; ++f) {
    int qrow = wrow0 + f * 16 + l16;
    qa[f][0] = *(const bf8*)&Qh[(size_t)qrow * 64 + quad * 8];
    qa[f][1] = *(const bf8*)&Qh[(size_t)qrow * 64 + 32 + quad * 8];
  }

  f4 o[2][4];
  float mrow[2][4], lrow[2][4];
#pragma unroll
  for (int f = 0; f < 2; ++f) {
#pragma unroll
    for (int dt = 0; dt < 4; ++dt) o[f][dt] = (f4)0.0f;
#pragma unroll
    for (int r = 0; r < 4; ++r) { mrow[f][r] = -3e38f; lrow[f][r] = 0.0f; }
  }

  const int nk = 2 * qt + 2;
  const int vd = t & 63, vrb = (t >> 6) * 16;     // V-transpose staging assignment

  for (int kt = 0; kt < nk; ++kt) {
    const int k0 = kt * 64;
    __syncthreads();
    // stage K rows (coalesced us8)
#pragma unroll
    for (int it = 0; it < 2; ++it) {
      int chunk = t + it * 256;
      int r = chunk >> 3, c8 = (chunk & 7) * 8;
      *(us8*)&Ks[r * 72 + c8] = *(const us8*)&Kh[(size_t)(k0 + r) * 64 + c8];
    }
    // stage V transposed: thread reads a column (coalesced across lanes),
    // writes contiguous us8 -> conflict-free (stride 36 dwords tiles 32 banks)
    {
      us8 w0, w1;
#pragma unroll
      for (int i = 0; i < 8; ++i)
        w0[i] = Vh[(size_t)(k0 + vrb + i) * 64 + vd];
#pragma unroll
      for (int i = 0; i < 8; ++i)
        w1[i] = Vh[(size_t)(k0 + vrb + 8 + i) * 64 + vd];
      *(us8*)&Vt[vd * 72 + vrb] = w0;
      *(us8*)&Vt[vd * 72 + vrb + 8] = w1;
    }
    __syncthreads();

    if (k0 > wrow0 + 31) continue;   // fully-masked tile for this wave

#pragma unroll
    for (int f = 0; f < 2; ++f) {
      const int rbase = wrow0 + f * 16 + quad * 4;
      // S = Q K^T  (16 x 64)
      f4 sc[4];
#pragma unroll
      for (int nt = 0; nt < 4; ++nt) {
        bf8 b0 = *(const bf8*)&Ks[(nt * 16 + l16) * 72 + quad * 8];
        bf8 b1 = *(const bf8*)&Ks[(nt * 16 + l16) * 72 + 32 + quad * 8];
        f4 z = (f4)0.0f;
        z = MFMA16(qa[f][0], b0, z);
        z = MFMA16(qa[f][1], b1, z);
        sc[nt] = z;
      }
      // scale + causal mask
      float sv[4][4];
#pragma unroll
      for (int nt = 0; nt < 4; ++nt) {
        int col = k0 + nt * 16 + l16;
#pragma unroll
        for (int r = 0; r < 4; ++r) {
          float v = sc[nt][r] * 0.125f;
          sv[nt][r] = (col > rbase + r) ? -3e38f : v;
        }
      }
      // online softmax
      float al[4];
#pragma unroll
      for (int r = 0; r < 4; ++r) {
        float mt = fmaxf(fmaxf(sv[0][r], sv[1][r]), fmaxf(sv[2][r], sv[3][r]));
#pragma unroll
        for (int off = 1; off < 16; off <<= 1)
          mt = fmaxf(mt, __shfl_xor(mt, off));
        float mn = fmaxf(mrow[f][r], mt);
        al[r] = __expf(mrow[f][r] - mn);
        mrow[f][r] = mn;
      }
      float ls[4] = {0.f, 0.f, 0.f, 0.f};
#pragma unroll
      for (int nt = 0; nt < 4; ++nt)
#pragma unroll
        for (int r = 0; r < 4; ++r) {
          float p = __expf(sv[nt][r] - mrow[f][r]);
          ls[r] += p;
          Ps[wave * 2304 + (f * 16 + quad * 4 + r) * 72 + nt * 16 + l16] = f2b(p);
        }
#pragma unroll
      for (int r = 0; r < 4; ++r) {
#pragma unroll
        for (int off = 1; off < 16; off <<= 1) ls[r] += __shfl_xor(ls[r], off);
        lrow[f][r] = lrow[f][r] * al[r] + ls[r];
      }
#pragma unroll
      for (int dt = 0; dt < 4; ++dt)
#pragma unroll
        for (int r = 0; r < 4; ++r) o[f][dt][r] *= al[r];
    }

    __threadfence_block();   // order Ps writes before A-layout reads

    // O += P V
    bf8 pa[2][2];
#pragma unroll
    for (int f = 0; f < 2; ++f) {
      pa[f][0] = *(const bf8*)&Ps[wave * 2304 + (f * 16 + l16) * 72 + quad * 8];
      pa[f][1] = *(const bf8*)&Ps[wave * 2304 + (f * 16 + l16) * 72 + 32 + quad * 8];
    }
#pragma unroll
    for (int dt = 0; dt < 4; ++dt) {
      bf8 vb0 = *(const bf8*)&Vt[(dt * 16 + l16) * 72 + quad * 8];
      bf8 vb1 = *(const bf8*)&Vt[(dt * 16 + l16) * 72 + 32 + quad * 8];
#pragma unroll
      for (int f = 0; f < 2; ++f) {
        o[f][dt] = MFMA16(pa[f][0], vb0, o[f][dt]);
        o[f][dt] = MFMA16(pa[f][1], vb1, o[f][dt]);
      }
    }
  }

  // epilogue: ctx in (b, s, E) bf16
#pragma unroll
  for (int f = 0; f < 2; ++f)
#pragma unroll
    for (int dt = 0; dt < 4; ++dt)
#pragma unroll
      for (int r = 0; r < 4; ++r) {
        float val = o[f][dt][r] / lrow[f][r];
        int row = wrow0 + f * 16 + quad * 4 + r;
        size_t idx = ((size_t)(b * 2048 + row)) * 1024 + h * 64 + dt * 16 + l16;
        ctx[idx] = f2b(val);
      }
}

// ---------------- output projection GEMM (fp32 out) ----------------
__global__ __launch_bounds__(256) void gemm_out_kernel(
    const unsigned short* __restrict__ A,    // ctx bf16 4096x1024
    const unsigned short* __restrict__ Wt,   // Wd^T bf16 1024x1024
    const float* __restrict__ bias, float* __restrict__ out) {
  __shared__ unsigned short As[128 * LDSK];
  __shared__ unsigned short Bs[128 * LDSK];
  const int t = threadIdx.x;
  const int wave = t >> 6, lane = t & 63, quad = lane >> 4, l16 = lane & 15;
  const int wm = (wave >> 1) * 64, wn = (wave & 1) * 64;
  const int m0 = blockIdx.y * 128, n0 = blockIdx.x * 128;

  f4 acc[4][4];
#pragma unroll
  for (int mi = 0; mi < 4; ++mi)
#pragma unroll
    for (int ni = 0; ni < 4; ++ni) acc[mi][ni] = (f4)0.0f;

  for (int k0 = 0; k0 < 1024; k0 += 32) {
    __syncthreads();
#pragma unroll
    for (int it = 0; it < 2; ++it) {
      int chunk = t + it * 256;
      int row = chunk >> 2, c8 = (chunk & 3) * 8;
      *(us8*)&As[row * LDSK + c8] =
          *(const us8*)&A[(size_t)(m0 + row) * 1024 + k0 + c8];
      *(us8*)&Bs[row * LDSK + c8] =
          *(const us8*)&Wt[(size_t)(n0 + row) * 1024 + k0 + c8];
    }
    __syncthreads();
    bf8 a[4], b[4];
#pragma unroll
    for (int mi = 0; mi < 4; ++mi)
      a[mi] = *(const bf8*)&As[(wm + mi * 16 + l16) * LDSK + quad * 8];
#pragma unroll
    for (int ni = 0; ni < 4; ++ni)
      b[ni] = *(const bf8*)&Bs[(wn + ni * 16 + l16) * LDSK + quad * 8];
#pragma unroll
    for (int mi = 0; mi < 4; ++mi)
#pragma unroll
      for (int ni = 0; ni < 4; ++ni)
        acc[mi][ni] = MFMA16(a[mi], b[ni], acc[mi][ni]);
  }
#pragma unroll
  for (int ni = 0; ni < 4; ++ni) {
    int n = n0 + wn + ni * 16 + l16;
    float bv_ = bias[n];
#pragma unroll
    for (int mi = 0; mi < 4; ++mi) {
#pragma unroll
      for (int r = 0; r < 4; ++r) {
        int m = m0 + wm + mi * 16 + quad * 4 + r;
        out[(size_t)m * 1024 + n] = acc[mi][ni][r] + bv_;
      }
    }
  }
}

extern "C" void kernel_launch(void* const* d_in, const int* in_sizes, int n_in,
                              void* d_out, int out_size, void* d_ws, size_t ws_size,
                              hipStream_t stream) {
  const float* hidden = (const float*)d_in[0];
  const float* Wq = (const float*)d_in[1];
  const float* bq = (const float*)d_in[2];
  const float* Wk = (const float*)d_in[3];
  const float* bk = (const float*)d_in[4];
  const float* Wv = (const float*)d_in[5];
  const float* bv = (const float*)d_in[6];
  const float* Wd = (const float*)d_in[7];
  const float* bd = (const float*)d_in[8];
  float* out = (float*)d_out;

  char* ws = (char*)d_ws;
  unsigned short* Xb  = (unsigned short*)(ws);                    // 8 MB
  unsigned short* Wqt = (unsigned short*)(ws + ( 8ull << 20));    // 2 MB each
  unsigned short* Wkt = (unsigned short*)(ws + (10ull << 20));
  unsigned short* Wvt = (unsigned short*)(ws + (12ull << 20));
  unsigned short* Wdt = (unsigned short*)(ws + (14ull << 20));
  unsigned short* Qb  = (unsigned short*)(ws + (16ull << 20));    // 8 MB each
  unsigned short* Kb  = (unsigned short*)(ws + (24ull << 20));
  unsigned short* Vb  = (unsigned short*)(ws + (32ull << 20));
  unsigned short* Cb  = (unsigned short*)(ws + (40ull << 20));

  cvt_bf16_kernel<<<4096, 256, 0, stream>>>(hidden, Xb);
  dim3 tg(32, 32);
  transpose_cvt_kernel<<<tg, 256, 0, stream>>>(Wq, Wqt);
  transpose_cvt_kernel<<<tg, 256, 0, stream>>>(Wk, Wkt);
  transpose_cvt_kernel<<<tg, 256, 0, stream>>>(Wv, Wvt);
  transpose_cvt_kernel<<<tg, 256, 0, stream>>>(Wd, Wdt);
  gemm_qkv_kernel<<<dim3(8, 32, 3), 256, 0, stream>>>(
      Xb, Wqt, Wkt, Wvt, bq, bk, bv, Qb, Kb, Vb);
  flash_attn_kernel<<<512, 256, 0, stream>>>(Qb, Kb, Vb, Cb);
  gemm_out_kernel<<<dim3(8, 32), 256, 0, stream>>>(Cb, Wdt, bd, out);
}

// Round 3
// 240.927 us; speedup vs baseline: 1.4744x; 1.2359x over previous
//
#include <hip/hip_runtime.h>
#include <stdint.h>

typedef __bf16 bf8 __attribute__((ext_vector_type(8)));
typedef float f4 __attribute__((ext_vector_type(4)));
typedef unsigned short us8 __attribute__((ext_vector_type(8)));
typedef unsigned short us4 __attribute__((ext_vector_type(4)));

#define MFMA16(a, b, c) __builtin_amdgcn_mfma_f32_16x16x32_bf16(a, b, c, 0, 0, 0)

__device__ __forceinline__ unsigned short f2b(float f) {
  union { float f; unsigned u; } x; x.f = f;
  unsigned u = x.u;
  u += 0x7fffu + ((u >> 16) & 1u);   // RNE
  return (unsigned short)(u >> 16);
}

// pack bf16(a) into low half, bf16(b) into high half (round half-up)
__device__ __forceinline__ unsigned pk2(float a, float b) {
  union { float f; unsigned u; } ua, ub; ua.f = a; ub.f = b;
  return __builtin_amdgcn_perm(ub.u + 0x8000u, ua.u + 0x8000u, 0x07060302u);
}

// ---------------- fp32 -> bf16 convert (hidden states) ----------------
__global__ __launch_bounds__(256) void cvt_bf16_kernel(
    const float* __restrict__ x, unsigned short* __restrict__ y) {
  int i = blockIdx.x * 256 + threadIdx.x;          // one float4 per thread
  float4 v = ((const float4*)x)[i];
  us4 r = { f2b(v.x), f2b(v.y), f2b(v.z), f2b(v.w) };
  *(us4*)(y + (size_t)i * 4) = r;
}

// ---------------- fp32 W[k][n] -> bf16 Wt[n][k] ----------------
__global__ __launch_bounds__(256) void transpose_cvt_kernel(
    const float* __restrict__ W, unsigned short* __restrict__ Wt) {
  __shared__ float tile[32][33];
  int tx = threadIdx.x & 31, ty = threadIdx.x >> 5;   // 32 x 8
  int kb = blockIdx.x * 32, nb = blockIdx.y * 32;
#pragma unroll
  for (int j = 0; j < 32; j += 8)
    tile[ty + j][tx] = W[(size_t)(kb + ty + j) * 1024 + nb + tx];
  __syncthreads();
#pragma unroll
  for (int j = 0; j < 32; j += 8)
    Wt[(size_t)(nb + ty + j) * 1024 + kb + tx] = f2b(tile[tx][ty + j]);
}

// ---------------- QKV projection GEMM (+ fused RoPE for Q,K) ----------------
// C = X(4096x1024) @ W(1024x1024) + bias.
// Q: bf16 (bh,s,d) pre-scaled by 0.125*log2(e); K: bf16 (bh,s,d);
// V: bf16 TRANSPOSED (bh,d,s) for direct V^T fragment loads in flash.
#define LDSK 40   // padded LDS stride in bf16 elems

__global__ __launch_bounds__(256) void gemm_qkv_kernel(
    const unsigned short* __restrict__ X,
    const unsigned short* __restrict__ Wqt, const unsigned short* __restrict__ Wkt,
    const unsigned short* __restrict__ Wvt,
    const float* __restrict__ bq, const float* __restrict__ bk,
    const float* __restrict__ bv,
    unsigned short* __restrict__ Qo, unsigned short* __restrict__ Ko,
    unsigned short* __restrict__ Vo) {
  const unsigned short* Wt; const float* bias; unsigned short* out;
  if (blockIdx.z == 0)      { Wt = Wqt; bias = bq; out = Qo; }
  else if (blockIdx.z == 1) { Wt = Wkt; bias = bk; out = Ko; }
  else                      { Wt = Wvt; bias = bv; out = Vo; }

  __shared__ unsigned short As[128 * LDSK];
  __shared__ unsigned short Bs[128 * LDSK];
  const int t = threadIdx.x;
  const int wave = t >> 6, lane = t & 63, quad = lane >> 4, l16 = lane & 15;
  const int wm = (wave >> 1) * 64, wn = (wave & 1) * 64;
  const int m0 = blockIdx.y * 128, n0 = blockIdx.x * 128;

  f4 acc[4][4];
#pragma unroll
  for (int mi = 0; mi < 4; ++mi)
#pragma unroll
    for (int ni = 0; ni < 4; ++ni) acc[mi][ni] = (f4)0.0f;

  for (int k0 = 0; k0 < 1024; k0 += 32) {
    __syncthreads();
#pragma unroll
    for (int it = 0; it < 2; ++it) {
      int chunk = t + it * 256;                  // 0..511
      int row = chunk >> 2, c8 = (chunk & 3) * 8;
      *(us8*)&As[row * LDSK + c8] =
          *(const us8*)&X[(size_t)(m0 + row) * 1024 + k0 + c8];
      *(us8*)&Bs[row * LDSK + c8] =
          *(const us8*)&Wt[(size_t)(n0 + row) * 1024 + k0 + c8];
    }
    __syncthreads();
    bf8 a[4], b[4];
#pragma unroll
    for (int mi = 0; mi < 4; ++mi)
      a[mi] = *(const bf8*)&As[(wm + mi * 16 + l16) * LDSK + quad * 8];
#pragma unroll
    for (int ni = 0; ni < 4; ++ni)
      b[ni] = *(const bf8*)&Bs[(wn + ni * 16 + l16) * LDSK + quad * 8];
#pragma unroll
    for (int mi = 0; mi < 4; ++mi)
#pragma unroll
      for (int ni = 0; ni < 4; ++ni)
        acc[mi][ni] = MFMA16(a[mi], b[ni], acc[mi][ni]);
  }

  // ---- epilogue: bias (+ RoPE for Q,K), C/D layout col=l16, row=quad*4+r ----
  float biasv[4];
#pragma unroll
  for (int ni = 0; ni < 4; ++ni) biasv[ni] = bias[n0 + wn + ni * 16 + l16];

  if (blockIdx.z < 2) {
    // d = ni*16 + l16. Pair (d, d^16) == registers (ni=0, ni=1).
    const float kr = 13.287712379549449f / 32.0f;   // log2(10000)/32
    const float f0 = exp2f(-(float)l16 * kr);
    const float f1 = exp2f(-(float)(l16 + 16) * kr);
    // Q pre-scale: 1/sqrt(64) * log2(e) folded in so flash uses exp2 directly
    const float qs = (blockIdx.z == 0) ? 0.18033688011112042f : 1.0f;
#pragma unroll
    for (int mi = 0; mi < 4; ++mi) {
#pragma unroll
      for (int r = 0; r < 4; ++r) {
        int m = m0 + wm + mi * 16 + quad * 4 + r;
        float s = (float)(m & 2047);
        float s0, c0, s1, c1;
        __sincosf(s * f0, &s0, &c0);
        __sincosf(s * f1, &s1, &c1);
        float v0 = acc[mi][0][r] + biasv[0];
        float v1 = acc[mi][1][r] + biasv[1];
        acc[mi][0][r] = (v0 * c0 - v1 * s0) * qs;
        acc[mi][1][r] = (v1 * c1 - v0 * s1) * qs;
        acc[mi][2][r] = (acc[mi][2][r] + biasv[2]) * qs;
        acc[mi][3][r] = (acc[mi][3][r] + biasv[3]) * qs;
      }
    }
    // row-major (bh, s, d) store
#pragma unroll
    for (int ni = 0; ni < 4; ++ni) {
      int n = n0 + wn + ni * 16 + l16;
      int h = n >> 6, d = n & 63;
#pragma unroll
      for (int mi = 0; mi < 4; ++mi) {
#pragma unroll
        for (int r = 0; r < 4; ++r) {
          int m = m0 + wm + mi * 16 + quad * 4 + r;
          int b_ = m >> 11, s = m & 2047;
          out[(size_t)(((b_ << 4) | h) * 2048 + s) * 64 + d] = f2b(acc[mi][ni][r]);
        }
      }
    }
  } else {
    // V: transposed (bh, d, s) store, packed us4 along s
#pragma unroll
    for (int ni = 0; ni < 4; ++ni) {
      int n = n0 + wn + ni * 16 + l16;
      int h = n >> 6, d = n & 63;
#pragma unroll
      for (int mi = 0; mi < 4; ++mi) {
        int m = m0 + wm + mi * 16 + quad * 4;
        int b_ = m >> 11, s = m & 2047;
        us4 w = { f2b(acc[mi][ni][0] + biasv[ni]), f2b(acc[mi][ni][1] + biasv[ni]),
                  f2b(acc[mi][ni][2] + biasv[ni]), f2b(acc[mi][ni][3] + biasv[ni]) };
        *(us4*)&out[((size_t)(((b_ << 4) | h) * 64 + d)) * 2048 + s] = w;
      }
    }
  }
}

// ---------------- causal flash attention (S^T formulation) ----------------
// Br=128 (4 independent waves x 32 rows), Bc=64. No __syncthreads in k-loop:
// K and V^T fragments load directly from global (L1/L2-resident tiles).
// Each lane owns one q-row (col=l16 of S^T): softmax state is per-lane scalar.
__global__ __launch_bounds__(256) void flash_attn_kernel(
    const unsigned short* __restrict__ Q, const unsigned short* __restrict__ K,
    const unsigned short* __restrict__ Vt, unsigned short* __restrict__ ctx) {
  __shared__ unsigned short PsT[4][16 * 72];   // per-wave P^T tile [q][kk]

  const int t = threadIdx.x;
  const int wave = t >> 6, lane = t & 63, quad = lane >> 4, l16 = lane & 15;

  // balanced qtile map: CU gets qt pair {k, 15-k} -> constant work per CU
  const int id = blockIdx.x;
  const int bh = id & 31;
  const int j = id >> 5;                          // 0..15
  const int qt = (j >> 3) ? (15 - (j & 7)) : (j & 7);
  const int qbase = qt * 128;
  const int b = bh >> 4, h = bh & 15;

  const unsigned short* Qh = Q + (size_t)bh * 2048 * 64;
  const unsigned short* Kh = K + (size_t)bh * 2048 * 64;
  const unsigned short* Vh = Vt + (size_t)bh * 64 * 2048;

  const int wrow0 = qbase + wave * 32;            // wave's first q-row

  // Q fragments as B-operand: B[k=d][n=q], n=l16, k=quad*8+j
  bf8 qb[2][2];
#pragma unroll
  for (int f = 0; f < 2; ++f)
#pragma unroll
    for (int c = 0; c < 2; ++c)
      qb[f][c] = *(const bf8*)&Qh[(size_t)(wrow0 + f * 16 + l16) * 64 + c * 32 + quad * 8];

  // ones A-fragment for row-sum-via-MFMA
  us8 ones_u = { 0x3F80, 0x3F80, 0x3F80, 0x3F80, 0x3F80, 0x3F80, 0x3F80, 0x3F80 };
  bf8 ones = *(bf8*)&ones_u;

  f4 o[2][4];
  float mrow[2] = { -3e38f, -3e38f }, lrow[2] = { 0.0f, 0.0f };
#pragma unroll
  for (int f = 0; f < 2; ++f)
#pragma unroll
    for (int dt = 0; dt < 4; ++dt) o[f][dt] = (f4)0.0f;

  unsigned short* myP = &PsT[wave][0];
  const int nkw = (wrow0 >> 6) + 1;               // tiles this wave needs

  for (int kt = 0; kt < nkw; ++kt) {
    const int k0 = kt * 64;
    // K as A-operand: A[m=kk][k=d]; V^T as A-operand: A[m=d][k=kk]
    bf8 ka[4][2], va[4][2];
#pragma unroll
    for (int mt = 0; mt < 4; ++mt)
#pragma unroll
      for (int c = 0; c < 2; ++c)
        ka[mt][c] = *(const bf8*)&Kh[(size_t)(k0 + mt * 16 + l16) * 64 + c * 32 + quad * 8];
#pragma unroll
    for (int dt = 0; dt < 4; ++dt)
#pragma unroll
      for (int c = 0; c < 2; ++c)
        va[dt][c] = *(const bf8*)&Vh[(size_t)(dt * 16 + l16) * 2048 + k0 + c * 32 + quad * 8];

#pragma unroll
    for (int f = 0; f < 2; ++f) {
      const int q = wrow0 + f * 16 + l16;
      // S^T = K Q^T : lane holds rows kk=mt*16+quad*4+r, col q=l16 (log2 units)
      f4 sc[4];
#pragma unroll
      for (int mt = 0; mt < 4; ++mt) {
        f4 z = (f4)0.0f;
        z = MFMA16(ka[mt][0], qb[f][0], z);
        z = MFMA16(ka[mt][1], qb[f][1], z);
        sc[mt] = z;
      }
      // causal mask: only the diagonal tile needs it (wave-uniform branch)
      if (k0 + 63 > wrow0 + f * 16) {
#pragma unroll
        for (int mt = 0; mt < 4; ++mt)
#pragma unroll
          for (int r = 0; r < 4; ++r) {
            int kk = k0 + mt * 16 + quad * 4 + r;
            if (kk > q) sc[mt][r] = -3e38f;
          }
      }
      // row max: 15 in-lane + 2 shfl (quads hold different kk, same q)
      float mx = fmaxf(fmaxf(sc[0][0], sc[0][1]), fmaxf(sc[0][2], sc[0][3]));
#pragma unroll
      for (int mt = 1; mt < 4; ++mt)
        mx = fmaxf(mx, fmaxf(fmaxf(sc[mt][0], sc[mt][1]), fmaxf(sc[mt][2], sc[mt][3])));
      mx = fmaxf(mx, __shfl_xor(mx, 16));
      mx = fmaxf(mx, __shfl_xor(mx, 32));
      float mn = fmaxf(mrow[f], mx);
      float al = exp2f(mrow[f] - mn);
      mrow[f] = mn;
      // p = exp2(s - m); pack pairs with v_perm; 4 consecutive kk per lane -> b64
#pragma unroll
      for (int mt = 0; mt < 4; ++mt) {
        float p0 = exp2f(sc[mt][0] - mn), p1 = exp2f(sc[mt][1] - mn);
        float p2 = exp2f(sc[mt][2] - mn), p3 = exp2f(sc[mt][3] - mn);
        uint2 w = { pk2(p0, p1), pk2(p2, p3) };
        *(uint2*)&myP[l16 * 72 + mt * 16 + quad * 4] = w;
      }
#pragma unroll
      for (int dt = 0; dt < 4; ++dt) o[f][dt] *= al;
      __threadfence_block();   // drain ds_writes before B-frag reads (same wave)
      // P^T as B-operand: B[k=kk][n=q]
      bf8 pb0 = *(const bf8*)&myP[l16 * 72 + quad * 8];
      bf8 pb1 = *(const bf8*)&myP[l16 * 72 + 32 + quad * 8];
      // row-sum via MFMA on the idle matrix pipe (all C rows identical)
      f4 z2 = (f4)0.0f;
      z2 = MFMA16(ones, pb0, z2);
      z2 = MFMA16(ones, pb1, z2);
      lrow[f] = lrow[f] * al + z2[0];
      // O^T += V^T P^T
#pragma unroll
      for (int dt = 0; dt < 4; ++dt) {
        o[f][dt] = MFMA16(va[dt][0], pb0, o[f][dt]);
        o[f][dt] = MFMA16(va[dt][1], pb1, o[f][dt]);
      }
    }
  }

  // epilogue: O^T lane holds col q=l16, rows d=dt*16+quad*4+r -> ctx (b,s,E)
#pragma unroll
  for (int f = 0; f < 2; ++f) {
    float inv = 1.0f / lrow[f];
    int q = wrow0 + f * 16 + l16;
#pragma unroll
    for (int dt = 0; dt < 4; ++dt) {
      us4 w = { f2b(o[f][dt][0] * inv), f2b(o[f][dt][1] * inv),
                f2b(o[f][dt][2] * inv), f2b(o[f][dt][3] * inv) };
      *(us4*)&ctx[((size_t)(b * 2048 + q)) * 1024 + h * 64 + dt * 16 + quad * 4] = w;
    }
  }
}

// ---------------- output projection GEMM (fp32 out) ----------------
__global__ __launch_bounds__(256) void gemm_out_kernel(
    const unsigned short* __restrict__ A,    // ctx bf16 4096x1024
    const unsigned short* __restrict__ Wt,   // Wd^T bf16 1024x1024
    const float* __restrict__ bias, float* __restrict__ out) {
  __shared__ unsigned short As[128 * LDSK];
  __shared__ unsigned short Bs[128 * LDSK];
  const int t = threadIdx.x;
  const int wave = t >> 6, lane = t & 63, quad = lane >> 4, l16 = lane & 15;
  const int wm = (wave >> 1) * 64, wn = (wave & 1) * 64;
  const int m0 = blockIdx.y * 128, n0 = blockIdx.x * 128;

  f4 acc[4][4];
#pragma unroll
  for (int mi = 0; mi < 4; ++mi)
#pragma unroll
    for (int ni = 0; ni < 4; ++ni) acc[mi][ni] = (f4)0.0f;

  for (int k0 = 0; k0 < 1024; k0 += 32) {
    __syncthreads();
#pragma unroll
    for (int it = 0; it < 2; ++it) {
      int chunk = t + it * 256;
      int row = chunk >> 2, c8 = (chunk & 3) * 8;
      *(us8*)&As[row * LDSK + c8] =
          *(const us8*)&A[(size_t)(m0 + row) * 1024 + k0 + c8];
      *(us8*)&Bs[row * LDSK + c8] =
          *(const us8*)&Wt[(size_t)(n0 + row) * 1024 + k0 + c8];
    }
    __syncthreads();
    bf8 a[4], b[4];
#pragma unroll
    for (int mi = 0; mi < 4; ++mi)
      a[mi] = *(const bf8*)&As[(wm + mi * 16 + l16) * LDSK + quad * 8];
#pragma unroll
    for (int ni = 0; ni < 4; ++ni)
      b[ni] = *(const bf8*)&Bs[(wn + ni * 16 + l16) * LDSK + quad * 8];
#pragma unroll
    for (int mi = 0; mi < 4; ++mi)
#pragma unroll
      for (int ni = 0; ni < 4; ++ni)
        acc[mi][ni] = MFMA16(a[mi], b[ni], acc[mi][ni]);
  }
#pragma unroll
  for (int ni = 0; ni < 4; ++ni) {
    int n = n0 + wn + ni * 16 + l16;
    float bv_ = bias[n];
#pragma unroll
    for (int mi = 0; mi < 4; ++mi) {
#pragma unroll
      for (int r = 0; r < 4; ++r) {
        int m = m0 + wm + mi * 16 + quad * 4 + r;
        out[(size_t)m * 1024 + n] = acc[mi][ni][r] + bv_;
      }
    }
  }
}

extern "C" void kernel_launch(void* const* d_in, const int* in_sizes, int n_in,
                              void* d_out, int out_size, void* d_ws, size_t ws_size,
                              hipStream_t stream) {
  const float* hidden = (const float*)d_in[0];
  const float* Wq = (const float*)d_in[1];
  const float* bq = (const float*)d_in[2];
  const float* Wk = (const float*)d_in[3];
  const float* bk = (const float*)d_in[4];
  const float* Wv = (const float*)d_in[5];
  const float* bv = (const float*)d_in[6];
  const float* Wd = (const float*)d_in[7];
  const float* bd = (const float*)d_in[8];
  float* out = (float*)d_out;

  char* ws = (char*)d_ws;
  unsigned short* Xb  = (unsigned short*)(ws);                    // 8 MB
  unsigned short* Wqt = (unsigned short*)(ws + ( 8ull << 20));    // 2 MB each
  unsigned short* Wkt = (unsigned short*)(ws + (10ull << 20));
  unsigned short* Wvt = (unsigned short*)(ws + (12ull << 20));
  unsigned short* Wdt = (unsigned short*)(ws + (14ull << 20));
  unsigned short* Qb  = (unsigned short*)(ws + (16ull << 20));    // 8 MB each
  unsigned short* Kb  = (unsigned short*)(ws + (24ull << 20));
  unsigned short* Vb  = (unsigned short*)(ws + (32ull << 20));    // transposed (bh,d,s)
  unsigned short* Cb  = (unsigned short*)(ws + (40ull << 20));

  cvt_bf16_kernel<<<4096, 256, 0, stream>>>(hidden, Xb);
  dim3 tg(32, 32);
  transpose_cvt_kernel<<<tg, 256, 0, stream>>>(Wq, Wqt);
  transpose_cvt_kernel<<<tg, 256, 0, stream>>>(Wk, Wkt);
  transpose_cvt_kernel<<<tg, 256, 0, stream>>>(Wv, Wvt);
  transpose_cvt_kernel<<<tg, 256, 0, stream>>>(Wd, Wdt);
  gemm_qkv_kernel<<<dim3(8, 32, 3), 256, 0, stream>>>(
      Xb, Wqt, Wkt, Wvt, bq, bk, bv, Qb, Kb, Vb);
  flash_attn_kernel<<<512, 256, 0, stream>>>(Qb, Kb, Vb, Cb);
  gemm_out_kernel<<<dim3(8, 32), 256, 0, stream>>>(Cb, Wdt, bd, out);
}

// Round 4
// 236.063 us; speedup vs baseline: 1.5048x; 1.0206x over previous
//
#include <hip/hip_runtime.h>
#include <stdint.h>

typedef __bf16 bf8 __attribute__((ext_vector_type(8)));
typedef float f4 __attribute__((ext_vector_type(4)));
typedef float f16v __attribute__((ext_vector_type(16)));
typedef unsigned short us8 __attribute__((ext_vector_type(8)));
typedef unsigned short us4 __attribute__((ext_vector_type(4)));

#define MFMA16(a, b, c) __builtin_amdgcn_mfma_f32_16x16x32_bf16(a, b, c, 0, 0, 0)
#define MFMA32(a, b, c) __builtin_amdgcn_mfma_f32_32x32x16_bf16(a, b, c, 0, 0, 0)

__device__ __forceinline__ unsigned short f2b(float f) {
  union { float f; unsigned u; } x; x.f = f;
  unsigned u = x.u;
  u += 0x7fffu + ((u >> 16) & 1u);   // RNE
  return (unsigned short)(u >> 16);
}

// pack bf16(a) low half, bf16(b) high half (round half-up)
__device__ __forceinline__ unsigned pk2(float a, float b) {
  union { float f; unsigned u; } ua, ub; ua.f = a; ub.f = b;
  return __builtin_amdgcn_perm(ub.u + 0x8000u, ua.u + 0x8000u, 0x07060302u);
}

// ---------------- fp32 -> bf16 convert (hidden states) ----------------
__global__ __launch_bounds__(256) void cvt_bf16_kernel(
    const float* __restrict__ x, unsigned short* __restrict__ y) {
  int i = blockIdx.x * 256 + threadIdx.x;
  float4 v = ((const float4*)x)[i];
  us4 r = { f2b(v.x), f2b(v.y), f2b(v.z), f2b(v.w) };
  *(us4*)(y + (size_t)i * 4) = r;
}

// ---------------- fp32 W[k][n] -> bf16 Wt[n][k], 4 matrices ----------------
__global__ __launch_bounds__(256) void transpose_cvt4_kernel(
    const float* __restrict__ W0, const float* __restrict__ W1,
    const float* __restrict__ W2, const float* __restrict__ W3,
    unsigned short* __restrict__ T0, unsigned short* __restrict__ T1,
    unsigned short* __restrict__ T2, unsigned short* __restrict__ T3) {
  const float* W; unsigned short* Wt;
  if (blockIdx.z == 0)      { W = W0; Wt = T0; }
  else if (blockIdx.z == 1) { W = W1; Wt = T1; }
  else if (blockIdx.z == 2) { W = W2; Wt = T2; }
  else                      { W = W3; Wt = T3; }
  __shared__ float tile[32][33];
  int tx = threadIdx.x & 31, ty = threadIdx.x >> 5;   // 32 x 8
  int kb = blockIdx.x * 32, nb = blockIdx.y * 32;
#pragma unroll
  for (int j = 0; j < 32; j += 8)
    tile[ty + j][tx] = W[(size_t)(kb + ty + j) * 1024 + nb + tx];
  __syncthreads();
#pragma unroll
  for (int j = 0; j < 32; j += 8)
    Wt[(size_t)(nb + ty + j) * 1024 + kb + tx] = f2b(tile[tx][ty + j]);
}

// ---------------- QKV projection GEMM (+ fused RoPE for Q,K) ----------------
// Q: bf16 (bh,s,d) pre-scaled by 0.125*log2(e); K: bf16 (bh,s,d);
// V: bf16 TRANSPOSED (bh,d,s).
#define LDSK 40

__global__ __launch_bounds__(256) void gemm_qkv_kernel(
    const unsigned short* __restrict__ X,
    const unsigned short* __restrict__ Wqt, const unsigned short* __restrict__ Wkt,
    const unsigned short* __restrict__ Wvt,
    const float* __restrict__ bq, const float* __restrict__ bk,
    const float* __restrict__ bv,
    unsigned short* __restrict__ Qo, unsigned short* __restrict__ Ko,
    unsigned short* __restrict__ Vo) {
  const unsigned short* Wt; const float* bias; unsigned short* out;
  if (blockIdx.z == 0)      { Wt = Wqt; bias = bq; out = Qo; }
  else if (blockIdx.z == 1) { Wt = Wkt; bias = bk; out = Ko; }
  else                      { Wt = Wvt; bias = bv; out = Vo; }

  __shared__ unsigned short As[128 * LDSK];
  __shared__ unsigned short Bs[128 * LDSK];
  const int t = threadIdx.x;
  const int wave = t >> 6, lane = t & 63, quad = lane >> 4, l16 = lane & 15;
  const int wm = (wave >> 1) * 64, wn = (wave & 1) * 64;
  const int m0 = blockIdx.y * 128, n0 = blockIdx.x * 128;

  f4 acc[4][4];
#pragma unroll
  for (int mi = 0; mi < 4; ++mi)
#pragma unroll
    for (int ni = 0; ni < 4; ++ni) acc[mi][ni] = (f4)0.0f;

  for (int k0 = 0; k0 < 1024; k0 += 32) {
    __syncthreads();
#pragma unroll
    for (int it = 0; it < 2; ++it) {
      int chunk = t + it * 256;
      int row = chunk >> 2, c8 = (chunk & 3) * 8;
      *(us8*)&As[row * LDSK + c8] =
          *(const us8*)&X[(size_t)(m0 + row) * 1024 + k0 + c8];
      *(us8*)&Bs[row * LDSK + c8] =
          *(const us8*)&Wt[(size_t)(n0 + row) * 1024 + k0 + c8];
    }
    __syncthreads();
    bf8 a[4], b[4];
#pragma unroll
    for (int mi = 0; mi < 4; ++mi)
      a[mi] = *(const bf8*)&As[(wm + mi * 16 + l16) * LDSK + quad * 8];
#pragma unroll
    for (int ni = 0; ni < 4; ++ni)
      b[ni] = *(const bf8*)&Bs[(wn + ni * 16 + l16) * LDSK + quad * 8];
#pragma unroll
    for (int mi = 0; mi < 4; ++mi)
#pragma unroll
      for (int ni = 0; ni < 4; ++ni)
        acc[mi][ni] = MFMA16(a[mi], b[ni], acc[mi][ni]);
  }

  float biasv[4];
#pragma unroll
  for (int ni = 0; ni < 4; ++ni) biasv[ni] = bias[n0 + wn + ni * 16 + l16];

  if (blockIdx.z < 2) {
    const float kr = 13.287712379549449f / 32.0f;   // log2(10000)/32
    const float f0 = exp2f(-(float)l16 * kr);
    const float f1 = exp2f(-(float)(l16 + 16) * kr);
    const float qs = (blockIdx.z == 0) ? 0.18033688011112042f : 1.0f;
#pragma unroll
    for (int mi = 0; mi < 4; ++mi) {
#pragma unroll
      for (int r = 0; r < 4; ++r) {
        int m = m0 + wm + mi * 16 + quad * 4 + r;
        float s = (float)(m & 2047);
        float s0, c0, s1, c1;
        __sincosf(s * f0, &s0, &c0);
        __sincosf(s * f1, &s1, &c1);
        float v0 = acc[mi][0][r] + biasv[0];
        float v1 = acc[mi][1][r] + biasv[1];
        acc[mi][0][r] = (v0 * c0 - v1 * s0) * qs;
        acc[mi][1][r] = (v1 * c1 - v0 * s1) * qs;
        acc[mi][2][r] = (acc[mi][2][r] + biasv[2]) * qs;
        acc[mi][3][r] = (acc[mi][3][r] + biasv[3]) * qs;
      }
    }
#pragma unroll
    for (int ni = 0; ni < 4; ++ni) {
      int n = n0 + wn + ni * 16 + l16;
      int h = n >> 6, d = n & 63;
#pragma unroll
      for (int mi = 0; mi < 4; ++mi) {
#pragma unroll
        for (int r = 0; r < 4; ++r) {
          int m = m0 + wm + mi * 16 + quad * 4 + r;
          int b_ = m >> 11, s = m & 2047;
          out[(size_t)(((b_ << 4) | h) * 2048 + s) * 64 + d] = f2b(acc[mi][ni][r]);
        }
      }
    }
  } else {
    // V: transposed (bh, d, s) store
#pragma unroll
    for (int ni = 0; ni < 4; ++ni) {
      int n = n0 + wn + ni * 16 + l16;
      int h = n >> 6, d = n & 63;
#pragma unroll
      for (int mi = 0; mi < 4; ++mi) {
        int m = m0 + wm + mi * 16 + quad * 4;
        int b_ = m >> 11, s = m & 2047;
        us4 w = { f2b(acc[mi][ni][0] + biasv[ni]), f2b(acc[mi][ni][1] + biasv[ni]),
                  f2b(acc[mi][ni][2] + biasv[ni]), f2b(acc[mi][ni][3] + biasv[ni]) };
        *(us4*)&out[((size_t)(((b_ << 4) | h) * 64 + d)) * 2048 + s] = w;
      }
    }
  }
}

// ---------------- causal flash attention (S^T, 32x32 MFMA, dbuf) ----------------
// Br=128 (4 waves x 32 q-rows), Bc=64. Lane owns one q-column of S^T.
// K/V fragments double-buffered from global; only LDS use is the P round-trip.
#define PST 72   // P^T LDS stride (us), 16B-aligned

__global__ __launch_bounds__(256, 2) void flash_attn_kernel(
    const unsigned short* __restrict__ Q, const unsigned short* __restrict__ K,
    const unsigned short* __restrict__ Vt, unsigned short* __restrict__ ctx) {
  __shared__ unsigned short PsT[4][32 * PST];   // per-wave P^T [q][kk]

  const int t = threadIdx.x;
  const int wave = t >> 6, lane = t & 63;
  const int l32 = lane & 31, hl = lane >> 5;

  // balanced qtile map: CU gets qt pair {k, 15-k}
  const int id = blockIdx.x;
  const int bh = id & 31;
  const int j = id >> 5;
  const int qt = (j >> 3) ? (15 - (j & 7)) : (j & 7);
  const int qbase = qt * 128;
  const int b = bh >> 4, h = bh & 15;

  const unsigned short* Qh = Q + (size_t)bh * 2048 * 64;
  const unsigned short* Kh = K + (size_t)bh * 2048 * 64;
  const unsigned short* Vh = Vt + (size_t)bh * 64 * 2048;

  const int wrow0 = qbase + wave * 32;
  const int q = wrow0 + l32;                    // lane's q-column

  // Q as B-operand: B[k=d][n=q]; chunk c covers d = c*16 + hl*8 + j
  bf8 qb[4];
#pragma unroll
  for (int c = 0; c < 4; ++c)
    qb[c] = *(const bf8*)&Qh[(size_t)q * 64 + c * 16 + hl * 8];

  f16v o0 = (f16v)0.0f, o1 = (f16v)0.0f;        // O^T: d-tiles 0..31, 32..63
  float mrow = -3e38f, lrow = 0.0f;

  unsigned short* myP = &PsT[wave][0];
  const int nkw = (wrow0 >> 6) + 1;

  bf8 kfA[2][4], vfA[2][4], kfB[2][4], vfB[2][4];

  auto loadK = [&](bf8 (&kf)[2][4], int k0) {
#pragma unroll
    for (int mt = 0; mt < 2; ++mt)
#pragma unroll
      for (int c = 0; c < 4; ++c)
        kf[mt][c] = *(const bf8*)&Kh[(size_t)(k0 + mt * 32 + l32) * 64 + c * 16 + hl * 8];
  };
  auto loadV = [&](bf8 (&vf)[2][4], int k0) {
#pragma unroll
    for (int dt = 0; dt < 2; ++dt)
#pragma unroll
      for (int c = 0; c < 4; ++c)
        vf[dt][c] = *(const bf8*)&Vh[(size_t)(dt * 32 + l32) * 2048 + k0 + c * 16 + hl * 8];
  };

  auto step = [&](int k0, bf8 (&kf)[2][4], bf8 (&vf)[2][4]) {
    // S^T = K Q^T : two 32x32 tiles over kk
    f16v s0 = (f16v)0.0f, s1 = (f16v)0.0f;
#pragma unroll
    for (int c = 0; c < 4; ++c) {
      s0 = MFMA32(kf[0][c], qb[c], s0);
      s1 = MFMA32(kf[1][c], qb[c], s1);
    }
    // causal mask: only the diagonal tile (wave-uniform branch)
    if (k0 + 64 > wrow0) {
#pragma unroll
      for (int g = 0; g < 4; ++g)
#pragma unroll
        for (int i = 0; i < 4; ++i) {
          int kk = k0 + g * 8 + hl * 4 + i;     // C layout: row=(reg&3)+8*(reg>>2)+4*hl
          if (kk > q) s0[g * 4 + i] = -3e38f;
          if (kk + 32 > q) s1[g * 4 + i] = -3e38f;
        }
    }
    // col-max: 31 in-lane + one shfl (lane^32 holds the other kk half)
    float mx = fmaxf(s0[0], s1[0]);
#pragma unroll
    for (int i = 1; i < 16; ++i) mx = fmaxf(mx, fmaxf(s0[i], s1[i]));
    mx = fmaxf(mx, __shfl_xor(mx, 32));
    float mn = fmaxf(mrow, mx);
    float al = exp2f(mrow - mn);
    mrow = mn;
    // p = exp2(s - m), pack to bf16, write P^T[q][kk]; in-lane partial sum
    float sum = 0.0f;
#pragma unroll
    for (int g = 0; g < 4; ++g) {
      float p0 = exp2f(s0[g * 4 + 0] - mn), p1 = exp2f(s0[g * 4 + 1] - mn);
      float p2 = exp2f(s0[g * 4 + 2] - mn), p3 = exp2f(s0[g * 4 + 3] - mn);
      sum += (p0 + p1) + (p2 + p3);
      uint2 w = { pk2(p0, p1), pk2(p2, p3) };
      *(uint2*)&myP[l32 * PST + g * 8 + hl * 4] = w;
      float r0 = exp2f(s1[g * 4 + 0] - mn), r1 = exp2f(s1[g * 4 + 1] - mn);
      float r2 = exp2f(s1[g * 4 + 2] - mn), r3 = exp2f(s1[g * 4 + 3] - mn);
      sum += (r0 + r1) + (r2 + r3);
      uint2 w2 = { pk2(r0, r1), pk2(r2, r3) };
      *(uint2*)&myP[l32 * PST + 32 + g * 8 + hl * 4] = w2;
    }
    // rescale O
#pragma unroll
    for (int i = 0; i < 16; ++i) { o0[i] *= al; o1[i] *= al; }
    // order ds_writes before ds_reads (LDS only — does NOT drain vmcnt)
    asm volatile("s_waitcnt lgkmcnt(0)" ::: "memory");
    // P^T as B-operand: B[k=kk][n=q]
    bf8 pb[4];
#pragma unroll
    for (int c = 0; c < 4; ++c)
      pb[c] = *(const bf8*)&myP[l32 * PST + c * 16 + hl * 8];
    // O^T += V^T P^T
#pragma unroll
    for (int c = 0; c < 4; ++c) {
      o0 = MFMA32(vf[0][c], pb[c], o0);
      o1 = MFMA32(vf[1][c], pb[c], o1);
    }
    // l update (sum shfl overlaps PV MFMAs)
    sum += __shfl_xor(sum, 32);
    lrow = lrow * al + sum;
  };

  loadK(kfA, 0); loadV(vfA, 0);
  int kt = 0;
  while (true) {
    if (kt + 1 < nkw) { loadK(kfB, (kt + 1) * 64); loadV(vfB, (kt + 1) * 64); }
    step(kt * 64, kfA, vfA);
    ++kt; if (kt >= nkw) break;
    if (kt + 1 < nkw) { loadK(kfA, (kt + 1) * 64); loadV(vfA, (kt + 1) * 64); }
    step(kt * 64, kfB, vfB);
    ++kt; if (kt >= nkw) break;
  }

  // epilogue: O^T lane holds col q, rows d = dt*32 + g*8 + hl*4 + i
  float inv = 1.0f / lrow;
#pragma unroll
  for (int g = 0; g < 4; ++g) {
    int d0 = g * 8 + hl * 4;
    us4 w0 = { f2b(o0[g * 4 + 0] * inv), f2b(o0[g * 4 + 1] * inv),
               f2b(o0[g * 4 + 2] * inv), f2b(o0[g * 4 + 3] * inv) };
    *(us4*)&ctx[((size_t)(b * 2048 + q)) * 1024 + h * 64 + d0] = w0;
    us4 w1 = { f2b(o1[g * 4 + 0] * inv), f2b(o1[g * 4 + 1] * inv),
               f2b(o1[g * 4 + 2] * inv), f2b(o1[g * 4 + 3] * inv) };
    *(us4*)&ctx[((size_t)(b * 2048 + q)) * 1024 + h * 64 + 32 + d0] = w1;
  }
}

// ---------------- output projection GEMM (fp32 out) ----------------
__global__ __launch_bounds__(256) void gemm_out_kernel(
    const unsigned short* __restrict__ A,
    const unsigned short* __restrict__ Wt,
    const float* __restrict__ bias, float* __restrict__ out) {
  __shared__ unsigned short As[128 * LDSK];
  __shared__ unsigned short Bs[128 * LDSK];
  const int t = threadIdx.x;
  const int wave = t >> 6, lane = t & 63, quad = lane >> 4, l16 = lane & 15;
  const int wm = (wave >> 1) * 64, wn = (wave & 1) * 64;
  const int m0 = blockIdx.y * 128, n0 = blockIdx.x * 128;

  f4 acc[4][4];
#pragma unroll
  for (int mi = 0; mi < 4; ++mi)
#pragma unroll
    for (int ni = 0; ni < 4; ++ni) acc[mi][ni] = (f4)0.0f;

  for (int k0 = 0; k0 < 1024; k0 += 32) {
    __syncthreads();
#pragma unroll
    for (int it = 0; it < 2; ++it) {
      int chunk = t + it * 256;
      int row = chunk >> 2, c8 = (chunk & 3) * 8;
      *(us8*)&As[row * LDSK + c8] =
          *(const us8*)&A[(size_t)(m0 + row) * 1024 + k0 + c8];
      *(us8*)&Bs[row * LDSK + c8] =
          *(const us8*)&Wt[(size_t)(n0 + row) * 1024 + k0 + c8];
    }
    __syncthreads();
    bf8 a[4], b[4];
#pragma unroll
    for (int mi = 0; mi < 4; ++mi)
      a[mi] = *(const bf8*)&As[(wm + mi * 16 + l16) * LDSK + quad * 8];
#pragma unroll
    for (int ni = 0; ni < 4; ++ni)
      b[ni] = *(const bf8*)&Bs[(wn + ni * 16 + l16) * LDSK + quad * 8];
#pragma unroll
    for (int mi = 0; mi < 4; ++mi)
#pragma unroll
      for (int ni = 0; ni < 4; ++ni)
        acc[mi][ni] = MFMA16(a[mi], b[ni], acc[mi][ni]);
  }
#pragma unroll
  for (int ni = 0; ni < 4; ++ni) {
    int n = n0 + wn + ni * 16 + l16;
    float bv_ = bias[n];
#pragma unroll
    for (int mi = 0; mi < 4; ++mi) {
#pragma unroll
      for (int r = 0; r < 4; ++r) {
        int m = m0 + wm + mi * 16 + quad * 4 + r;
        out[(size_t)m * 1024 + n] = acc[mi][ni][r] + bv_;
      }
    }
  }
}

extern "C" void kernel_launch(void* const* d_in, const int* in_sizes, int n_in,
                              void* d_out, int out_size, void* d_ws, size_t ws_size,
                              hipStream_t stream) {
  const float* hidden = (const float*)d_in[0];
  const float* Wq = (const float*)d_in[1];
  const float* bq = (const float*)d_in[2];
  const float* Wk = (const float*)d_in[3];
  const float* bk = (const float*)d_in[4];
  const float* Wv = (const float*)d_in[5];
  const float* bv = (const float*)d_in[6];
  const float* Wd = (const float*)d_in[7];
  const float* bd = (const float*)d_in[8];
  float* out = (float*)d_out;

  char* ws = (char*)d_ws;
  unsigned short* Xb  = (unsigned short*)(ws);
  unsigned short* Wqt = (unsigned short*)(ws + ( 8ull << 20));
  unsigned short* Wkt = (unsigned short*)(ws + (10ull << 20));
  unsigned short* Wvt = (unsigned short*)(ws + (12ull << 20));
  unsigned short* Wdt = (unsigned short*)(ws + (14ull << 20));
  unsigned short* Qb  = (unsigned short*)(ws + (16ull << 20));
  unsigned short* Kb  = (unsigned short*)(ws + (24ull << 20));
  unsigned short* Vb  = (unsigned short*)(ws + (32ull << 20));   // (bh,d,s)
  unsigned short* Cb  = (unsigned short*)(ws + (40ull << 20));

  cvt_bf16_kernel<<<4096, 256, 0, stream>>>(hidden, Xb);
  transpose_cvt4_kernel<<<dim3(32, 32, 4), 256, 0, stream>>>(
      Wq, Wk, Wv, Wd, Wqt, Wkt, Wvt, Wdt);
  gemm_qkv_kernel<<<dim3(8, 32, 3), 256, 0, stream>>>(
      Xb, Wqt, Wkt, Wvt, bq, bk, bv, Qb, Kb, Vb);
  flash_attn_kernel<<<512, 256, 0, stream>>>(Qb, Kb, Vb, Cb);
  gemm_out_kernel<<<dim3(8, 32), 256, 0, stream>>>(Cb, Wdt, bd, out);
}

// Round 5
// 225.334 us; speedup vs baseline: 1.5764x; 1.0476x over previous
//
#include <hip/hip_runtime.h>
#include <stdint.h>

typedef __bf16 bf8 __attribute__((ext_vector_type(8)));
typedef float f4 __attribute__((ext_vector_type(4)));
typedef float f16v __attribute__((ext_vector_type(16)));
typedef unsigned short us8 __attribute__((ext_vector_type(8)));
typedef unsigned short us4 __attribute__((ext_vector_type(4)));

#define MFMA16(a, b, c) __builtin_amdgcn_mfma_f32_16x16x32_bf16(a, b, c, 0, 0, 0)
#define MFMA32(a, b, c) __builtin_amdgcn_mfma_f32_32x32x16_bf16(a, b, c, 0, 0, 0)

__device__ __forceinline__ unsigned short f2b(float f) {
  union { float f; unsigned u; } x; x.f = f;
  unsigned u = x.u;
  u += 0x7fffu + ((u >> 16) & 1u);   // RNE
  return (unsigned short)(u >> 16);
}

// pack bf16(a) low half, bf16(b) high half (round half-up)
__device__ __forceinline__ unsigned pk2(float a, float b) {
  union { float f; unsigned u; } ua, ub; ua.f = a; ub.f = b;
  return __builtin_amdgcn_perm(ub.u + 0x8000u, ua.u + 0x8000u, 0x07060302u);
}

// async global->LDS 16B per lane; lds dest = wave-uniform base + lane*16
__device__ __forceinline__ void gload16(const void* g, void* l) {
  __builtin_amdgcn_global_load_lds(
      (const __attribute__((address_space(1))) void*)g,
      (__attribute__((address_space(3))) void*)l, 16, 0, 0);
}

// ---------------- fp32 -> bf16 convert (hidden states) ----------------
__global__ __launch_bounds__(256) void cvt_bf16_kernel(
    const float* __restrict__ x, unsigned short* __restrict__ y) {
  int i = blockIdx.x * 256 + threadIdx.x;
  float4 v = ((const float4*)x)[i];
  us4 r = { f2b(v.x), f2b(v.y), f2b(v.z), f2b(v.w) };
  *(us4*)(y + (size_t)i * 4) = r;
}

// ---------------- fp32 W[k][n] -> bf16 Wt[n][k], 4 matrices ----------------
__global__ __launch_bounds__(256) void transpose_cvt4_kernel(
    const float* __restrict__ W0, const float* __restrict__ W1,
    const float* __restrict__ W2, const float* __restrict__ W3,
    unsigned short* __restrict__ T0, unsigned short* __restrict__ T1,
    unsigned short* __restrict__ T2, unsigned short* __restrict__ T3) {
  const float* W; unsigned short* Wt;
  if (blockIdx.z == 0)      { W = W0; Wt = T0; }
  else if (blockIdx.z == 1) { W = W1; Wt = T1; }
  else if (blockIdx.z == 2) { W = W2; Wt = T2; }
  else                      { W = W3; Wt = T3; }
  __shared__ float tile[32][33];
  int tx = threadIdx.x & 31, ty = threadIdx.x >> 5;   // 32 x 8
  int kb = blockIdx.x * 32, nb = blockIdx.y * 32;
#pragma unroll
  for (int j = 0; j < 32; j += 8)
    tile[ty + j][tx] = W[(size_t)(kb + ty + j) * 1024 + nb + tx];
  __syncthreads();
#pragma unroll
  for (int j = 0; j < 32; j += 8)
    Wt[(size_t)(nb + ty + j) * 1024 + kb + tx] = f2b(tile[tx][ty + j]);
}

// ---------------- QKV projection GEMM (+ fused RoPE for Q,K) ----------------
// Q: bf16 (bh,s,d) pre-scaled by 0.125*log2(e); K: bf16 (bh,s,d);
// V: bf16 TRANSPOSED (bh,d,s). LDS tight stride 32 (global_load_lds dest rule).
__global__ __launch_bounds__(256) void gemm_qkv_kernel(
    const unsigned short* __restrict__ X,
    const unsigned short* __restrict__ Wqt, const unsigned short* __restrict__ Wkt,
    const unsigned short* __restrict__ Wvt,
    const float* __restrict__ bq, const float* __restrict__ bk,
    const float* __restrict__ bv,
    unsigned short* __restrict__ Qo, unsigned short* __restrict__ Ko,
    unsigned short* __restrict__ Vo) {
  const unsigned short* Wt; const float* bias; unsigned short* out;
  if (blockIdx.z == 0)      { Wt = Wqt; bias = bq; out = Qo; }
  else if (blockIdx.z == 1) { Wt = Wkt; bias = bk; out = Ko; }
  else                      { Wt = Wvt; bias = bv; out = Vo; }

  __shared__ unsigned short As[128 * 32];
  __shared__ unsigned short Bs[128 * 32];
  const int t = threadIdx.x;
  const int wave = t >> 6, lane = t & 63, quad = lane >> 4, l16 = lane & 15;
  const int wm = (wave >> 1) * 64, wn = (wave & 1) * 64;
  const int m0 = blockIdx.y * 128, n0 = blockIdx.x * 128;

  f4 acc[4][4];
#pragma unroll
  for (int mi = 0; mi < 4; ++mi)
#pragma unroll
    for (int ni = 0; ni < 4; ++ni) acc[mi][ni] = (f4)0.0f;

  for (int k0 = 0; k0 < 1024; k0 += 32) {
    __syncthreads();
#pragma unroll
    for (int it = 0; it < 2; ++it) {
      int chunk = it * 256 + wave * 64 + lane;      // 16B chunk index
      int row = chunk >> 2, c = chunk & 3;
      gload16(&X[(size_t)(m0 + row) * 1024 + k0 + c * 8],
              &As[(size_t)(it * 256 + wave * 64) * 8]);
      gload16(&Wt[(size_t)(n0 + row) * 1024 + k0 + c * 8],
              &Bs[(size_t)(it * 256 + wave * 64) * 8]);
    }
    __syncthreads();
    bf8 a[4], b[4];
#pragma unroll
    for (int mi = 0; mi < 4; ++mi)
      a[mi] = *(const bf8*)&As[(wm + mi * 16 + l16) * 32 + quad * 8];
#pragma unroll
    for (int ni = 0; ni < 4; ++ni)
      b[ni] = *(const bf8*)&Bs[(wn + ni * 16 + l16) * 32 + quad * 8];
#pragma unroll
    for (int mi = 0; mi < 4; ++mi)
#pragma unroll
      for (int ni = 0; ni < 4; ++ni)
        acc[mi][ni] = MFMA16(a[mi], b[ni], acc[mi][ni]);
  }

  float biasv[4];
#pragma unroll
  for (int ni = 0; ni < 4; ++ni) biasv[ni] = bias[n0 + wn + ni * 16 + l16];

  if (blockIdx.z < 2) {
    const float kr = 13.287712379549449f / 32.0f;   // log2(10000)/32
    const float f0 = exp2f(-(float)l16 * kr);
    const float f1 = exp2f(-(float)(l16 + 16) * kr);
    const float qs = (blockIdx.z == 0) ? 0.18033688011112042f : 1.0f;
#pragma unroll
    for (int mi = 0; mi < 4; ++mi) {
#pragma unroll
      for (int r = 0; r < 4; ++r) {
        int m = m0 + wm + mi * 16 + quad * 4 + r;
        float s = (float)(m & 2047);
        float s0, c0, s1, c1;
        __sincosf(s * f0, &s0, &c0);
        __sincosf(s * f1, &s1, &c1);
        float v0 = acc[mi][0][r] + biasv[0];
        float v1 = acc[mi][1][r] + biasv[1];
        acc[mi][0][r] = (v0 * c0 - v1 * s0) * qs;
        acc[mi][1][r] = (v1 * c1 - v0 * s1) * qs;
        acc[mi][2][r] = (acc[mi][2][r] + biasv[2]) * qs;
        acc[mi][3][r] = (acc[mi][3][r] + biasv[3]) * qs;
      }
    }
#pragma unroll
    for (int ni = 0; ni < 4; ++ni) {
      int n = n0 + wn + ni * 16 + l16;
      int h = n >> 6, d = n & 63;
#pragma unroll
      for (int mi = 0; mi < 4; ++mi) {
#pragma unroll
        for (int r = 0; r < 4; ++r) {
          int m = m0 + wm + mi * 16 + quad * 4 + r;
          int b_ = m >> 11, s = m & 2047;
          out[(size_t)(((b_ << 4) | h) * 2048 + s) * 64 + d] = f2b(acc[mi][ni][r]);
        }
      }
    }
  } else {
    // V: transposed (bh, d, s) store
#pragma unroll
    for (int ni = 0; ni < 4; ++ni) {
      int n = n0 + wn + ni * 16 + l16;
      int h = n >> 6, d = n & 63;
#pragma unroll
      for (int mi = 0; mi < 4; ++mi) {
        int m = m0 + wm + mi * 16 + quad * 4;
        int b_ = m >> 11, s = m & 2047;
        us4 w = { f2b(acc[mi][ni][0] + biasv[ni]), f2b(acc[mi][ni][1] + biasv[ni]),
                  f2b(acc[mi][ni][2] + biasv[ni]), f2b(acc[mi][ni][3] + biasv[ni]) };
        *(us4*)&out[((size_t)(((b_ << 4) | h) * 64 + d)) * 2048 + s] = w;
      }
    }
  }
}

// ---------------- causal flash attention (S^T, 32x32 MFMA, no LDS) ----------------
// Br=128 (4 waves x 32 q-cols), Bc=64. Lane owns one q-column of S^T.
// P transposed C-layout -> B-operand purely in registers via shfl_xor(.,32).
// K double-buffered; V issued early each tile (consumed after softmax).
__global__ __launch_bounds__(256, 2) void flash_attn_kernel(
    const unsigned short* __restrict__ Q, const unsigned short* __restrict__ K,
    const unsigned short* __restrict__ Vt, unsigned short* __restrict__ ctx) {
  const int t = threadIdx.x;
  const int lane = t & 63;
  const int wave = t >> 6, l32 = lane & 31, hl = lane >> 5;

  // balanced qtile map: CU gets qt pair {k, 15-k}
  const int id = blockIdx.x;
  const int bh = id & 31;
  const int j = id >> 5;
  const int qt = (j >> 3) ? (15 - (j & 7)) : (j & 7);
  const int qbase = qt * 128;
  const int b = bh >> 4, h = bh & 15;

  const unsigned short* Qh = Q + (size_t)bh * 2048 * 64;
  const unsigned short* Kh = K + (size_t)bh * 2048 * 64;
  const unsigned short* Vh = Vt + (size_t)bh * 64 * 2048;

  const int wrow0 = qbase + wave * 32;
  const int q = wrow0 + l32;                    // lane's q-column

  // Q as B-operand: B[k=d][n=q]; chunk c covers d = c*16 + hl*8 + j
  bf8 qb[4];
#pragma unroll
  for (int c = 0; c < 4; ++c)
    qb[c] = *(const bf8*)&Qh[(size_t)q * 64 + c * 16 + hl * 8];

  f16v o0 = (f16v)0.0f, o1 = (f16v)0.0f;        // O^T: d 0..31, 32..63
  float mrow = -3e38f, lrow = 0.0f;
  const int nkw = (wrow0 >> 6) + 1;

  bf8 kfA[2][4], kfB[2][4], vf[2][4];

  auto loadK = [&](bf8 (&kf)[2][4], int k0) {
#pragma unroll
    for (int mt = 0; mt < 2; ++mt)
#pragma unroll
      for (int c = 0; c < 4; ++c)
        kf[mt][c] = *(const bf8*)&Kh[(size_t)(k0 + mt * 32 + l32) * 64 + c * 16 + hl * 8];
  };
  auto loadV = [&](int k0) {
#pragma unroll
    for (int dt = 0; dt < 2; ++dt)
#pragma unroll
      for (int c = 0; c < 4; ++c)
        vf[dt][c] = *(const bf8*)&Vh[(size_t)(dt * 32 + l32) * 2048 + k0 + c * 16 + hl * 8];
  };

  auto step = [&](int k0, bf8 (&kf)[2][4]) {
    // S^T = K Q^T : two 32x32 tiles over kk (reg a=g*4+i <-> kk=g*8+hl*4+i)
    f16v s0 = (f16v)0.0f, s1 = (f16v)0.0f;
#pragma unroll
    for (int c = 0; c < 4; ++c) {
      s0 = MFMA32(kf[0][c], qb[c], s0);
      s1 = MFMA32(kf[1][c], qb[c], s1);
    }
    // causal mask: only diagonal tiles (wave-uniform branch)
    if (k0 + 64 > wrow0) {
#pragma unroll
      for (int g = 0; g < 4; ++g)
#pragma unroll
        for (int i = 0; i < 4; ++i) {
          int kk = k0 + g * 8 + hl * 4 + i;
          if (kk > q) s0[g * 4 + i] = -3e38f;
          if (kk + 32 > q) s1[g * 4 + i] = -3e38f;
        }
    }
    // col-max: 31 in-lane + one shfl (lane^32 holds the other kk half)
    float mx = fmaxf(s0[0], s1[0]);
#pragma unroll
    for (int i = 1; i < 16; ++i) mx = fmaxf(mx, fmaxf(s0[i], s1[i]));
    mx = fmaxf(mx, __shfl_xor(mx, 32));
    float mn = fmaxf(mrow, mx);
    float al = exp2f(mrow - mn);
    mrow = mn;
    // p = exp2(s - m) packed to bf16: pd2[G] covers kk = G*8 + hl*4 + {0..3}
    uint2 pd2[8];
    float sum = 0.0f;
#pragma unroll
    for (int g = 0; g < 4; ++g) {
      float p0 = exp2f(s0[g * 4 + 0] - mn), p1 = exp2f(s0[g * 4 + 1] - mn);
      float p2 = exp2f(s0[g * 4 + 2] - mn), p3 = exp2f(s0[g * 4 + 3] - mn);
      sum += (p0 + p1) + (p2 + p3);
      pd2[g].x = pk2(p0, p1); pd2[g].y = pk2(p2, p3);
      float r0 = exp2f(s1[g * 4 + 0] - mn), r1 = exp2f(s1[g * 4 + 1] - mn);
      float r2 = exp2f(s1[g * 4 + 2] - mn), r3 = exp2f(s1[g * 4 + 3] - mn);
      sum += (r0 + r1) + (r2 + r3);
      pd2[4 + g].x = pk2(r0, r1); pd2[4 + g].y = pk2(r2, r3);
    }
    // rescale O
#pragma unroll
    for (int i = 0; i < 16; ++i) { o0[i] *= al; o1[i] *= al; }
    // O^T += V^T P^T ; P B-fragment built in-register:
    // chunk c needs kk = 16c + hl*8 + j  ->  own pd2[2c(+1)] + partner's via shfl^32
#pragma unroll
    for (int c = 0; c < 4; ++c) {
      uint2 lo = pd2[2 * c], hi = pd2[2 * c + 1];
      unsigned sx = hl ? lo.x : hi.x, sy = hl ? lo.y : hi.y;
      unsigned rx = __shfl_xor(sx, 32), ry = __shfl_xor(sy, 32);
      union { uint4 u; bf8 v; } fr;
      fr.u.x = hl ? rx : lo.x;
      fr.u.y = hl ? ry : lo.y;
      fr.u.z = hl ? hi.x : rx;
      fr.u.w = hl ? hi.y : ry;
      o0 = MFMA32(vf[0][c], fr.v, o0);
      o1 = MFMA32(vf[1][c], fr.v, o1);
    }
    sum += __shfl_xor(sum, 32);
    lrow = lrow * al + sum;
  };

  loadK(kfA, 0);
  int kt = 0;
  while (true) {
    loadV(kt * 64);
    if (kt + 1 < nkw) loadK(kfB, (kt + 1) * 64);
    step(kt * 64, kfA);
    ++kt; if (kt >= nkw) break;
    loadV(kt * 64);
    if (kt + 1 < nkw) loadK(kfA, (kt + 1) * 64);
    step(kt * 64, kfB);
    ++kt; if (kt >= nkw) break;
  }

  // epilogue: O^T lane holds col q, rows d = g*8 + hl*4 + i (o1: +32)
  float inv = 1.0f / lrow;
#pragma unroll
  for (int g = 0; g < 4; ++g) {
    int d0 = g * 8 + hl * 4;
    us4 w0 = { f2b(o0[g * 4 + 0] * inv), f2b(o0[g * 4 + 1] * inv),
               f2b(o0[g * 4 + 2] * inv), f2b(o0[g * 4 + 3] * inv) };
    *(us4*)&ctx[((size_t)(b * 2048 + q)) * 1024 + h * 64 + d0] = w0;
    us4 w1 = { f2b(o1[g * 4 + 0] * inv), f2b(o1[g * 4 + 1] * inv),
               f2b(o1[g * 4 + 2] * inv), f2b(o1[g * 4 + 3] * inv) };
    *(us4*)&ctx[((size_t)(b * 2048 + q)) * 1024 + h * 64 + 32 + d0] = w1;
  }
}

// ---------------- output projection GEMM (fp32 out), 64x128 tiles ----------------
__global__ __launch_bounds__(256) void gemm_out_kernel(
    const unsigned short* __restrict__ A,
    const unsigned short* __restrict__ Wt,
    const float* __restrict__ bias, float* __restrict__ out) {
  __shared__ unsigned short As[64 * 32];
  __shared__ unsigned short Bs[128 * 32];
  const int t = threadIdx.x;
  const int wave = t >> 6, lane = t & 63, quad = lane >> 4, l16 = lane & 15;
  const int wm = (wave & 1) * 32, wn = (wave >> 1) * 64;
  const int m0 = blockIdx.y * 64, n0 = blockIdx.x * 128;

  f4 acc[2][4];
#pragma unroll
  for (int mi = 0; mi < 2; ++mi)
#pragma unroll
    for (int ni = 0; ni < 4; ++ni) acc[mi][ni] = (f4)0.0f;

  for (int k0 = 0; k0 < 1024; k0 += 32) {
    __syncthreads();
    {
      int chunk = wave * 64 + lane;                  // 0..255 -> A (64x32)
      int row = chunk >> 2, c = chunk & 3;
      gload16(&A[(size_t)(m0 + row) * 1024 + k0 + c * 8],
              &As[(size_t)(wave * 64) * 8]);
#pragma unroll
      for (int it = 0; it < 2; ++it) {
        int ch = it * 256 + wave * 64 + lane;        // 0..511 -> B (128x32)
        int rw = ch >> 2, cc = ch & 3;
        gload16(&Wt[(size_t)(n0 + rw) * 1024 + k0 + cc * 8],
                &Bs[(size_t)(it * 256 + wave * 64) * 8]);
      }
    }
    __syncthreads();
    bf8 a[2], b[4];
#pragma unroll
    for (int mi = 0; mi < 2; ++mi)
      a[mi] = *(const bf8*)&As[(wm + mi * 16 + l16) * 32 + quad * 8];
#pragma unroll
    for (int ni = 0; ni < 4; ++ni)
      b[ni] = *(const bf8*)&Bs[(wn + ni * 16 + l16) * 32 + quad * 8];
#pragma unroll
    for (int mi = 0; mi < 2; ++mi)
#pragma unroll
      for (int ni = 0; ni < 4; ++ni)
        acc[mi][ni] = MFMA16(a[mi], b[ni], acc[mi][ni]);
  }
#pragma unroll
  for (int ni = 0; ni < 4; ++ni) {
    int n = n0 + wn + ni * 16 + l16;
    float bv_ = bias[n];
#pragma unroll
    for (int mi = 0; mi < 2; ++mi) {
#pragma unroll
      for (int r = 0; r < 4; ++r) {
        int m = m0 + wm + mi * 16 + quad * 4 + r;
        out[(size_t)m * 1024 + n] = acc[mi][ni][r] + bv_;
      }
    }
  }
}

extern "C" void kernel_launch(void* const* d_in, const int* in_sizes, int n_in,
                              void* d_out, int out_size, void* d_ws, size_t ws_size,
                              hipStream_t stream) {
  const float* hidden = (const float*)d_in[0];
  const float* Wq = (const float*)d_in[1];
  const float* bq = (const float*)d_in[2];
  const float* Wk = (const float*)d_in[3];
  const float* bk = (const float*)d_in[4];
  const float* Wv = (const float*)d_in[5];
  const float* bv = (const float*)d_in[6];
  const float* Wd = (const float*)d_in[7];
  const float* bd = (const float*)d_in[8];
  float* out = (float*)d_out;

  char* ws = (char*)d_ws;
  unsigned short* Xb  = (unsigned short*)(ws);
  unsigned short* Wqt = (unsigned short*)(ws + ( 8ull << 20));
  unsigned short* Wkt = (unsigned short*)(ws + (10ull << 20));
  unsigned short* Wvt = (unsigned short*)(ws + (12ull << 20));
  unsigned short* Wdt = (unsigned short*)(ws + (14ull << 20));
  unsigned short* Qb  = (unsigned short*)(ws + (16ull << 20));
  unsigned short* Kb  = (unsigned short*)(ws + (24ull << 20));
  unsigned short* Vb  = (unsigned short*)(ws + (32ull << 20));   // (bh,d,s)
  unsigned short* Cb  = (unsigned short*)(ws + (40ull << 20));

  cvt_bf16_kernel<<<4096, 256, 0, stream>>>(hidden, Xb);
  transpose_cvt4_kernel<<<dim3(32, 32, 4), 256, 0, stream>>>(
      Wq, Wk, Wv, Wd, Wqt, Wkt, Wvt, Wdt);
  gemm_qkv_kernel<<<dim3(8, 32, 3), 256, 0, stream>>>(
      Xb, Wqt, Wkt, Wvt, bq, bk, bv, Qb, Kb, Vb);
  flash_attn_kernel<<<512, 256, 0, stream>>>(Qb, Kb, Vb, Cb);
  gemm_out_kernel<<<dim3(8, 64), 256, 0, stream>>>(Cb, Wdt, bd, out);
}